// Round 3
// baseline (1314.402 us; speedup 1.0000x reference)
//
#include <hip/hip_runtime.h>
#include <hip/hip_bf16.h>
#include <cstdint>
#include <cstddef>

// ---------------------------------------------------------------------------
// MeshMultiHeadHodgeLaplaceAttention  (b=2, n=2048, m=6144, k=4096, D=256, H=8)
//
// Heads are contiguous 32-channel blocks -> per-head einsums collapse into
// [M x K] @ [K x 256] GEMMs with per-(row, head) diagonal scales.
//   up:   T1 = d_1 @ eV ; *f_hval ; T2 = d_1^T @ T1s ; (*einv_hval in combine)
//   down: Y0 = eV*e_hval ; T3 = d_0^T @ Y0 ; *1/(v_hval+eps) ; T4 = d_0 @ T3s
//   out = (T2*einv_hval + T4) @ W_o
//
// Precision strategy: the comparison reference is numpy in FP32. The v-branch
// reciprocal 1/(v_hval+1e-6) amplifies hval rounding by ~3.5e4, so v_hval must
// match np's FP32 arithmetic (not be "more accurate"):
//   - projections: sequential __fmaf_rn over k (BLAS sgemm microkernel order)
//   - head-dot: numpy einsum SSE2 pattern - 4 stride-4 partials, mul+add
//     separately rounded, combined (s0+s2)+(s1+s3)
//   - /sqrtf(32), +1e-6f, 1/x all in IEEE fp32
// Amplified multiplicand chain {Qe,Ke,eV,T3,T4,W_o}: split-bf16 GEMM (hi/lo,
// 3 MFMA passes, ~1e-5 rel). Non-amplified {einv,f hvals, T1,T2}: plain bf16.
// ---------------------------------------------------------------------------

typedef __attribute__((ext_vector_type(4))) float f32x4;
typedef __attribute__((ext_vector_type(4))) unsigned short u16x4;
typedef __attribute__((ext_vector_type(8))) unsigned short u16x8;
typedef __attribute__((ext_vector_type(8))) __bf16 bf16x8;

static __device__ __forceinline__ unsigned short f2bf(float f) {
  uint32_t u = __builtin_bit_cast(uint32_t, f);
  uint32_t r = (u + 0x7FFFu + ((u >> 16) & 1u)) >> 16;  // RNE
  return (unsigned short)r;
}
static __device__ __forceinline__ float bf2f(unsigned short h) {
  return __builtin_bit_cast(float, (uint32_t)h << 16);
}

// ---------------------------------------------------------------------------
// GEMM: C[MxN] = A[MxK] * B[KxN], A and B fp32 (converted to bf16 hi(/lo) in
// LDS during staging), C fp32. N==256 (grid.y = 2, 128-col halves).
// TRANS_A: logical A[m][k] = G[k][m], G row length ldA.
// SPLIT: hi/lo 2-term split of both operands, 3 MFMA passes (drop lo*lo).
// 128x128 tile, BK=32, 4 waves in 2x2 grid, each 64x64 (4x4 16x16x32 frags).
// ---------------------------------------------------------------------------
template <bool TRANS_A, bool SPLIT>
__global__ __launch_bounds__(256) void gemm_f32(
    const float* __restrict__ A, const float* __restrict__ B,
    float* __restrict__ C, int M, int N, int K, int ldA,
    long long sA, long long sB, long long sC) {
  A += (long long)blockIdx.z * sA;
  B += (long long)blockIdx.z * sB;
  C += (long long)blockIdx.z * sC;
  const int m0 = blockIdx.x * 128, n0 = blockIdx.y * 128;

  constexpr int NBUF = SPLIT ? 4 : 2;
  // [0]=A_hi [1]=B_hi [2]=A_lo [3]=B_lo ; [row][k] with +8 pad
  __shared__ unsigned short lds[NBUF][128][40];

  const int tid = threadIdx.x;
  const int wid = tid >> 6, lane = tid & 63;
  const int wr = wid >> 1, wc = wid & 1;
  const int lr = lane & 15, kq = lane >> 4;
  const int rr = tid >> 3, cg = tid & 7;  // staging: 32 rows x 8 col-groups

  f32x4 acc[4][4] = {};

  for (int k0 = 0; k0 < K; k0 += 32) {
    // ---- stage A ----
    if (!TRANS_A) {
      #pragma unroll
      for (int i = 0; i < 4; ++i) {
        f32x4 v = *(const f32x4*)(A + (size_t)(m0 + rr + 32 * i) * ldA + k0 + cg * 4);
        u16x4 h = {f2bf(v[0]), f2bf(v[1]), f2bf(v[2]), f2bf(v[3])};
        *(u16x4*)&lds[0][rr + 32 * i][cg * 4] = h;
        if constexpr (SPLIT) {
          u16x4 l = {f2bf(v[0] - bf2f(h[0])), f2bf(v[1] - bf2f(h[1])),
                     f2bf(v[2] - bf2f(h[2])), f2bf(v[3] - bf2f(h[3]))};
          *(u16x4*)&lds[2][rr + 32 * i][cg * 4] = l;
        }
      }
    } else {
      #pragma unroll
      for (int jb = 0; jb < 4; ++jb) {
        f32x4 v = *(const f32x4*)(A + (size_t)(k0 + rr) * ldA + m0 + jb * 32 + cg * 4);
        #pragma unroll
        for (int jj = 0; jj < 4; ++jj) {
          unsigned short h = f2bf(v[jj]);
          lds[0][jb * 32 + cg * 4 + jj][rr] = h;
          if constexpr (SPLIT) lds[2][jb * 32 + cg * 4 + jj][rr] = f2bf(v[jj] - bf2f(h));
        }
      }
    }
    // ---- stage B (rows = k, transpose to [n][k]) ----
    #pragma unroll
    for (int jb = 0; jb < 4; ++jb) {
      f32x4 v = *(const f32x4*)(B + (size_t)(k0 + rr) * N + n0 + jb * 32 + cg * 4);
      #pragma unroll
      for (int jj = 0; jj < 4; ++jj) {
        unsigned short h = f2bf(v[jj]);
        lds[1][jb * 32 + cg * 4 + jj][rr] = h;
        if constexpr (SPLIT) lds[3][jb * 32 + cg * 4 + jj][rr] = f2bf(v[jj] - bf2f(h));
      }
    }
    __syncthreads();

    bf16x8 ah[4], bh[4], al[4], bl[4];
    #pragma unroll
    for (int i = 0; i < 4; ++i) {
      ah[i] = __builtin_bit_cast(bf16x8, *(const u16x8*)&lds[0][wr * 64 + i * 16 + lr][kq * 8]);
      bh[i] = __builtin_bit_cast(bf16x8, *(const u16x8*)&lds[1][wc * 64 + i * 16 + lr][kq * 8]);
      if constexpr (SPLIT) {
        al[i] = __builtin_bit_cast(bf16x8, *(const u16x8*)&lds[2][wr * 64 + i * 16 + lr][kq * 8]);
        bl[i] = __builtin_bit_cast(bf16x8, *(const u16x8*)&lds[3][wc * 64 + i * 16 + lr][kq * 8]);
      }
    }
    #pragma unroll
    for (int i = 0; i < 4; ++i)
      #pragma unroll
      for (int j = 0; j < 4; ++j) {
        acc[i][j] = __builtin_amdgcn_mfma_f32_16x16x32_bf16(ah[i], bh[j], acc[i][j], 0, 0, 0);
        if constexpr (SPLIT) {
          acc[i][j] = __builtin_amdgcn_mfma_f32_16x16x32_bf16(ah[i], bl[j], acc[i][j], 0, 0, 0);
          acc[i][j] = __builtin_amdgcn_mfma_f32_16x16x32_bf16(al[i], bh[j], acc[i][j], 0, 0, 0);
        }
      }
    __syncthreads();
  }

  // epilogue: D mapping col = lane&15, row = (lane>>4)*4 + q
  #pragma unroll
  for (int i = 0; i < 4; ++i)
    #pragma unroll
    for (int j = 0; j < 4; ++j) {
      float* cp = C + (size_t)(m0 + wr * 64 + i * 16 + kq * 4) * N + n0 + wc * 64 + j * 16 + lr;
      #pragma unroll
      for (int q = 0; q < 4; ++q) cp[(size_t)q * N] = acc[i][j][q];
    }
}

// ---------------------------------------------------------------------------
// v-pair hval replicating numpy fp32 arithmetic (feeds the reciprocal, which
// amplifies any deviation from the np reference by ~3.5e4):
//   q_j = sequential fmaf over i (BLAS sgemm microkernel: one accumulator,
//         fused FMA, k ascending)
//   head dot = numpy einsum SSE2 sum_of_products: 4 stride-4 partials,
//         separately-rounded mul+add, combined (s0+s2)+(s1+s3)
//   hval = p / sqrtf(32); inv = 1/(hval + 1e-6f)   (IEEE fp32 ops)
// One block per row (b*NV+pos).
// ---------------------------------------------------------------------------
__global__ __launch_bounds__(256) void vproj_hval_np(
    const float* __restrict__ X, const float* __restrict__ Wq,
    const float* __restrict__ Wk, float* __restrict__ hout, int P) {
  __shared__ float sx[256];
  __shared__ float sq[256], sk[256];
  const int row = blockIdx.x;
  const int j = threadIdx.x;
  sx[j] = X[(size_t)row * 256 + j];
  __syncthreads();
  float q = 0.0f, k = 0.0f;
  for (int i = 0; i < 256; ++i) {
    float xi = sx[i];
    q = __fmaf_rn(xi, Wq[i * 256 + j], q);
    k = __fmaf_rn(xi, Wk[i * 256 + j], k);
  }
  sq[j] = q;
  sk[j] = k;
  __syncthreads();
  if (j < 8) {
    const float* qq = &sq[j * 32];
    const float* kk = &sk[j * 32];
    float s0 = 0.0f, s1 = 0.0f, s2 = 0.0f, s3 = 0.0f;
    #pragma unroll 1
    for (int d = 0; d < 32; d += 4) {
      s0 = __fadd_rn(s0, __fmul_rn(qq[d + 0], kk[d + 0]));
      s1 = __fadd_rn(s1, __fmul_rn(qq[d + 1], kk[d + 1]));
      s2 = __fadd_rn(s2, __fmul_rn(qq[d + 2], kk[d + 2]));
      s3 = __fadd_rn(s3, __fmul_rn(qq[d + 3], kk[d + 3]));
    }
    float p = __fadd_rn(__fadd_rn(s0, s2), __fadd_rn(s1, s3));
    float hval = __fdiv_rn(p, sqrtf(32.0f));
    float inv = __fdiv_rn(1.0f, __fadd_rn(hval, 1e-6f));
    const int b = row / P, pos = row - b * P;
    hout[((size_t)b * 8 + j) * P + pos] = inv;
  }
}

// hval = rowwise per-head dot of fp32 Q,K. One wave per row.
__global__ __launch_bounds__(256) void dot_hval(
    const float* __restrict__ Q, const float* __restrict__ K,
    float* __restrict__ hout, int P) {
  const int wid = threadIdx.x >> 6, lane = threadIdx.x & 63;
  const int row = blockIdx.x * 4 + wid;
  f32x4 q = *(const f32x4*)(Q + (size_t)row * 256 + lane * 4);
  f32x4 k = *(const f32x4*)(K + (size_t)row * 256 + lane * 4);
  float p = q[0] * k[0] + q[1] * k[1] + q[2] * k[2] + q[3] * k[3];
  p += __shfl_xor(p, 1);
  p += __shfl_xor(p, 2);
  p += __shfl_xor(p, 4);
  if ((lane & 7) == 0) {
    const int head = lane >> 3;
    const int b = row / P, pos = row % P;
    hout[((size_t)b * 8 + head) * P + pos] = p * 0.17677669529663687f;
  }
}

// out_f32 = in_f32 * hval[(b, head(col), pos)]
__global__ void scale_f32(const float* __restrict__ in, float* __restrict__ out,
                          const float* __restrict__ h, int P, long long nq) {
  long long i = (long long)blockIdx.x * blockDim.x + threadIdx.x;
  const long long stride = (long long)gridDim.x * blockDim.x;
  for (; i < nq; i += stride) {
    f32x4 v = ((const f32x4*)in)[i];
    long long r = i >> 6;
    int c0 = ((int)i & 63) << 2;
    int b = (int)(r / P), pos = (int)(r - (long long)b * P);
    float s = h[((size_t)b * 8 + (c0 >> 5)) * P + pos];
    ((f32x4*)out)[i] = v * s;
  }
}

// S = T2 * einv_hval + T4   (S aliases T4: same-index RMW)
__global__ void combine_scale(const float* __restrict__ T2,
                              const float* __restrict__ T4,
                              const float* __restrict__ h,
                              float* __restrict__ S, int P, long long nq) {
  long long i = (long long)blockIdx.x * blockDim.x + threadIdx.x;
  const long long stride = (long long)gridDim.x * blockDim.x;
  for (; i < nq; i += stride) {
    long long r = i >> 6;
    int c0 = ((int)i & 63) << 2;
    int b = (int)(r / P), pos = (int)(r - (long long)b * P);
    float s = h[((size_t)b * 8 + (c0 >> 5)) * P + pos];
    f32x4 a = ((const f32x4*)T2)[i];
    f32x4 d = ((const f32x4*)T4)[i];
    ((f32x4*)S)[i] = a * s + d;
  }
}

// ---------------------------------------------------------------------------
extern "C" void kernel_launch(void* const* d_in, const int* in_sizes, int n_in,
                              void* d_out, int out_size, void* d_ws, size_t ws_size,
                              hipStream_t stream) {
  const float* x_v = (const float*)d_in[0];
  const float* x_e = (const float*)d_in[1];
  const float* x_f = (const float*)d_in[2];
  const float* d0  = (const float*)d_in[3];   // (2, 6144, 2048)
  const float* d1  = (const float*)d_in[4];   // (2, 4096, 6144)
  const float* W_vq   = (const float*)d_in[5];
  const float* W_vk   = (const float*)d_in[6];
  const float* W_eq   = (const float*)d_in[7];
  const float* W_ek   = (const float*)d_in[8];
  const float* W_einvq= (const float*)d_in[9];
  const float* W_einvk= (const float*)d_in[10];
  const float* W_ev   = (const float*)d_in[11];
  const float* W_fq   = (const float*)d_in[12];
  const float* W_fk   = (const float*)d_in[13];
  const float* W_o    = (const float*)d_in[14];
  float* out = (float*)d_out;

  const int B = 2, NV = 2048, ME = 6144, KF = 4096;
  const int RE = B * ME;   // 12288
  const int RF = B * KF;   // 8192

  char* ws = (char*)d_ws;
  size_t o = 0;
  auto alloc = [&](size_t bytes) { size_t r = o; o = (o + bytes + 255) & ~255ULL; return r; };

  size_t hv_e    = alloc((size_t)B * 8 * ME * 4);
  size_t hv_einv = alloc((size_t)B * 8 * ME * 4);
  size_t hv_f    = alloc((size_t)B * 8 * KF * 4);
  size_t hv_v    = alloc((size_t)B * 8 * NV * 4);
  const size_t SLAB = (size_t)RE * 256 * 4;  // 12.58 MB
  size_t slabA = alloc(SLAB);   // eVf
  size_t slabB = alloc(SLAB);   // Y0 -> T2
  size_t slabC = alloc(SLAB);   // Q  -> T4/S
  size_t slabD = alloc(SLAB);   // K  -> T3|T3s -> T1
  size_t slabE = alloc((size_t)RF * 256 * 4);  // T1s (8.39 MB)

  float* pHvE  = (float*)(ws + hv_e);
  float* pHvEi = (float*)(ws + hv_einv);
  float* pHvF  = (float*)(ws + hv_f);
  float* pHvV  = (float*)(ws + hv_v);
  float* pEVf = (float*)(ws + slabA);
  float* pB   = (float*)(ws + slabB);
  float* pC   = (float*)(ws + slabC);
  float* pD   = (float*)(ws + slabD);
  float* pT3  = pD;
  float* pT3s = (float*)(ws + slabD + (size_t)B * NV * 256 * 4);
  float* pT1  = pD;
  float* pT1s = (float*)(ws + slabE);

  dim3 blk(256);

  // --- hvals ---
  vproj_hval_np<<<B * NV, blk, 0, stream>>>(x_v, W_vq, W_vk, pHvV, NV);
  // e pair (feeds Y0 -> amplified chain): split precision
  gemm_f32<false, true><<<dim3(RE / 128, 2, 1), blk, 0, stream>>>(x_e, W_eq, pC, RE, 256, 256, 256, 0, 0, 0);
  gemm_f32<false, true><<<dim3(RE / 128, 2, 1), blk, 0, stream>>>(x_e, W_ek, pD, RE, 256, 256, 256, 0, 0, 0);
  dot_hval<<<RE / 4, blk, 0, stream>>>(pC, pD, pHvE, ME);
  // einv pair (scales non-amplified T2): plain bf16
  gemm_f32<false, false><<<dim3(RE / 128, 2, 1), blk, 0, stream>>>(x_e, W_einvq, pC, RE, 256, 256, 256, 0, 0, 0);
  gemm_f32<false, false><<<dim3(RE / 128, 2, 1), blk, 0, stream>>>(x_e, W_einvk, pD, RE, 256, 256, 256, 0, 0, 0);
  dot_hval<<<RE / 4, blk, 0, stream>>>(pC, pD, pHvEi, ME);
  // f pair: plain bf16
  gemm_f32<false, false><<<dim3(RF / 128, 2, 1), blk, 0, stream>>>(x_f, W_fq, pC, RF, 256, 256, 256, 0, 0, 0);
  gemm_f32<false, false><<<dim3(RF / 128, 2, 1), blk, 0, stream>>>(x_f, W_fk, pD, RF, 256, 256, 256, 0, 0, 0);
  dot_hval<<<RF / 4, blk, 0, stream>>>(pC, pD, pHvF, KF);

  // --- eV (amplified chain): split ---
  gemm_f32<false, true><<<dim3(RE / 128, 2, 1), blk, 0, stream>>>(x_e, W_ev, pEVf, RE, 256, 256, 256, 0, 0, 0);
  // Y0 = eV * e_hval (fp32)
  scale_f32<<<3072, blk, 0, stream>>>(pEVf, pB, pHvE, ME, (long long)RE * 64);

  // --- down branch (amplified): split GEMMs ---
  gemm_f32<true, true><<<dim3(NV / 128, 2, 2), blk, 0, stream>>>(
      d0, pB, pT3, NV, 256, ME, NV, (long long)ME * NV, (long long)ME * 256, (long long)NV * 256);
  scale_f32<<<1024, blk, 0, stream>>>(pT3, pT3s, pHvV, NV, (long long)B * NV * 64);
  gemm_f32<false, true><<<dim3(ME / 128, 2, 2), blk, 0, stream>>>(
      d0, pT3s, pC, ME, 256, NV, NV, (long long)ME * NV, (long long)NV * 256, (long long)ME * 256);

  // --- up branch (non-amplified): plain bf16 ---
  gemm_f32<false, false><<<dim3(KF / 128, 2, 2), blk, 0, stream>>>(
      d1, pEVf, pT1, KF, 256, ME, ME, (long long)KF * ME, (long long)ME * 256, (long long)KF * 256);
  scale_f32<<<2048, blk, 0, stream>>>(pT1, pT1s, pHvF, KF, (long long)RF * 64);
  gemm_f32<true, false><<<dim3(ME / 128, 2, 2), blk, 0, stream>>>(
      d1, pT1s, pB, ME, 256, KF, ME, (long long)KF * ME, (long long)KF * 256, (long long)ME * 256);

  // --- combine + output projection (amplified values in S): split ---
  combine_scale<<<3072, blk, 0, stream>>>(pB, pC, pHvEi, pC, ME, (long long)RE * 64);
  gemm_f32<false, true><<<dim3(RE / 128, 2, 1), blk, 0, stream>>>(pC, W_o, out, RE, 256, 256, 256, 0, 0, 0);
}

// Round 4
// 767.305 us; speedup vs baseline: 1.7130x; 1.7130x over previous
//
#include <hip/hip_runtime.h>
#include <hip/hip_bf16.h>
#include <cstdint>
#include <cstddef>

// ---------------------------------------------------------------------------
// MeshMultiHeadHodgeLaplaceAttention  (b=2, n=2048, m=6144, k=4096, D=256, H=8)
//
//   up:   T1 = d_1 @ eV ; *f_hval ; T2 = d_1^T @ T1s ; (*einv_hval in combine)
//   down: Y0 = eV*e_hval ; T3 = d_0^T @ Y0 ; *1/(v_hval+eps) ; T4 = d_0 @ T3s
//   out = (T2*einv_hval + T4) @ W_o
//
// Precision (validated in round 3): v_hval replicates numpy fp32 exactly;
// amplified chain {eq/ek, eV, T3, T4, out} = split-bf16 (hi/lo, 3 MFMA);
// rest plain bf16.
//
// Round-4 structure: split-K fills the grid (384 blocks on big GEMMs),
// B operands pre-transposed to bf16 [n][k] (vectorized staging),
// XCD-bijective block swizzle pairs the two N-halves per A-panel.
// ---------------------------------------------------------------------------

typedef __attribute__((ext_vector_type(4))) float f32x4;
typedef __attribute__((ext_vector_type(4))) unsigned short u16x4;
typedef __attribute__((ext_vector_type(8))) unsigned short u16x8;
typedef __attribute__((ext_vector_type(8))) __bf16 bf16x8;

static __device__ __forceinline__ unsigned short f2bf(float f) {
  uint32_t u = __builtin_bit_cast(uint32_t, f);
  uint32_t r = (u + 0x7FFFu + ((u >> 16) & 1u)) >> 16;  // RNE
  return (unsigned short)r;
}
static __device__ __forceinline__ float bf2f(unsigned short h) {
  return __builtin_bit_cast(float, (uint32_t)h << 16);
}

// ---------------------------------------------------------------------------
// GEMM: C[M x 256] = A[M x K] * B, A fp32 (bf16-converted in LDS), B bf16
// pre-transposed [256][K] (hi and optional lo). Split-K: blockIdx.z packs
// (batch, split); each split writes its own C slab (reduced later).
// TRANS_A: logical A[m][k] = G[k][m] (G row length ldA).
// 128x128 tile, BK=32, 4 waves 2x2, 4x4 16x16x32 frags each.
// ---------------------------------------------------------------------------
template <bool TRANS_A, bool SPLIT>
__global__ __launch_bounds__(256) void gemm_ws(
    const float* __restrict__ A, const unsigned short* __restrict__ Bh,
    const unsigned short* __restrict__ Bl, float* __restrict__ C,
    int K, int ldA, int S, long long sA, long long sB, long long sC) {
  const int z = blockIdx.z;
  const int batch = z / S, split = z - batch * S;
  A += (long long)batch * sA;
  Bh += (long long)batch * sB;
  if constexpr (SPLIT) Bl += (long long)batch * sB;
  C += (long long)z * sC;

  // XCD-bijective swizzle over (x,y); swizzled index has y fastest so the
  // two N-halves of one A-panel are adjacent -> same XCD chunk -> L2 hit.
  const int gx = gridDim.x, nwg = gx * 2;
  const int wid = blockIdx.x + gx * blockIdx.y;  // HW-linear within z-slice
  const int q = nwg >> 3, r = nwg & 7;
  const int xcd = wid & 7, posn = wid >> 3;
  const int swz = (xcd < r ? xcd * (q + 1) : r * (q + 1) + (xcd - r) * q) + posn;
  const int m0 = (swz >> 1) * 128, n0 = (swz & 1) * 128;

  const int kLen = K / S, k0base = split * kLen;

  constexpr int NBUF = SPLIT ? 4 : 2;
  __shared__ unsigned short lds[NBUF][128][40];  // [0]=Ah [1]=Bh [2]=Al [3]=Bl

  const int t = threadIdx.x;
  const int wid4 = t >> 6, lane = t & 63;
  const int wr = wid4 >> 1, wc = wid4 & 1;
  const int lr = lane & 15, kq = lane >> 4;

  f32x4 acc[4][4] = {};

  for (int kk = 0; kk < kLen; kk += 32) {
    const int kb = k0base + kk;
    // ---- stage A ----
    if constexpr (!TRANS_A) {
      #pragma unroll
      for (int a = 0; a < 4; ++a) {
        int idx = t + 256 * a;            // 1024 f32x4 = 128 rows x 8 quads
        int row = idx >> 3, qd = idx & 7;
        f32x4 v = *(const f32x4*)(A + (size_t)(m0 + row) * ldA + kb + qd * 4);
        u16x4 h = {f2bf(v[0]), f2bf(v[1]), f2bf(v[2]), f2bf(v[3])};
        *(u16x4*)&lds[0][row][qd * 4] = h;
        if constexpr (SPLIT) {
          u16x4 l = {f2bf(v[0] - bf2f(h[0])), f2bf(v[1] - bf2f(h[1])),
                     f2bf(v[2] - bf2f(h[2])), f2bf(v[3] - bf2f(h[3]))};
          *(u16x4*)&lds[2][row][qd * 4] = l;
        }
      }
    } else {
      #pragma unroll
      for (int a = 0; a < 4; ++a) {
        int idx = t + 256 * a;            // 32 k-rows x 32 m-quads
        int kr = idx >> 5, mq = (idx & 31) * 4;
        f32x4 v = *(const f32x4*)(A + (size_t)(kb + kr) * ldA + m0 + mq);
        #pragma unroll
        for (int j = 0; j < 4; ++j) {
          unsigned short h = f2bf(v[j]);
          lds[0][mq + j][kr] = h;
          if constexpr (SPLIT) lds[2][mq + j][kr] = f2bf(v[j] - bf2f(h));
        }
      }
    }
    // ---- stage B (pre-transposed [n][K], coalesced u16x8) ----
    {
      int row = t >> 2, c = (t & 3) * 8;
      #pragma unroll
      for (int a = 0; a < 2; ++a) {
        int rr2 = row + 64 * a;
        *(u16x8*)&lds[1][rr2][c] = *(const u16x8*)(Bh + (size_t)(n0 + rr2) * K + kb + c);
        if constexpr (SPLIT)
          *(u16x8*)&lds[3][rr2][c] = *(const u16x8*)(Bl + (size_t)(n0 + rr2) * K + kb + c);
      }
    }
    __syncthreads();

    bf16x8 ah[4], bh[4], al[4], bl[4];
    #pragma unroll
    for (int i = 0; i < 4; ++i) {
      ah[i] = __builtin_bit_cast(bf16x8, *(const u16x8*)&lds[0][wr * 64 + i * 16 + lr][kq * 8]);
      bh[i] = __builtin_bit_cast(bf16x8, *(const u16x8*)&lds[1][wc * 64 + i * 16 + lr][kq * 8]);
      if constexpr (SPLIT) {
        al[i] = __builtin_bit_cast(bf16x8, *(const u16x8*)&lds[2][wr * 64 + i * 16 + lr][kq * 8]);
        bl[i] = __builtin_bit_cast(bf16x8, *(const u16x8*)&lds[3][wc * 64 + i * 16 + lr][kq * 8]);
      }
    }
    #pragma unroll
    for (int i = 0; i < 4; ++i)
      #pragma unroll
      for (int j = 0; j < 4; ++j) {
        acc[i][j] = __builtin_amdgcn_mfma_f32_16x16x32_bf16(ah[i], bh[j], acc[i][j], 0, 0, 0);
        if constexpr (SPLIT) {
          acc[i][j] = __builtin_amdgcn_mfma_f32_16x16x32_bf16(ah[i], bl[j], acc[i][j], 0, 0, 0);
          acc[i][j] = __builtin_amdgcn_mfma_f32_16x16x32_bf16(al[i], bh[j], acc[i][j], 0, 0, 0);
        }
      }
    __syncthreads();
  }

  // epilogue: D mapping col = lane&15, row = (lane>>4)*4 + q
  #pragma unroll
  for (int i = 0; i < 4; ++i)
    #pragma unroll
    for (int j = 0; j < 4; ++j) {
      float* cp = C + (size_t)(m0 + wr * 64 + i * 16 + kq * 4) * 256 + n0 + wc * 64 + j * 16 + lr;
      #pragma unroll
      for (int qq = 0; qq < 4; ++qq) cp[(size_t)qq * 256] = acc[i][j][qq];
    }
}

// ---------------------------------------------------------------------------
// xpose_cvt: in fp32 [NB][S][P][256] (ldS between splits, inB between batches)
//   -> out bf16 [NB][256][P] hi (+lo), after summing S slabs (fixed order)
//   and optional scale by h[(b*8+head)*P + pos] (head = channel>>5).
// 64x64 LDS tile; coalesced reads and writes.
// ---------------------------------------------------------------------------
__global__ __launch_bounds__(256) void xpose_cvt(
    const float* __restrict__ in, unsigned short* __restrict__ out_hi,
    unsigned short* __restrict__ out_lo, const float* __restrict__ h,
    int S, long long ldS, long long inB, int P) {
  __shared__ unsigned short thi[64][72], tlo[64][72];
  const int b = blockIdx.z;
  const int r0 = blockIdx.x * 64;   // pos tile
  const int c0 = blockIdx.y * 64;   // channel tile
  const float* src = in + (long long)b * inB;
  const int t = threadIdx.x;
  #pragma unroll
  for (int a = 0; a < 4; ++a) {
    int idx = t + 256 * a;          // 0..1023 : 64 rows x 16 col-quads
    int tr = idx >> 4, tc = (idx & 15) * 4;
    const float* p = src + (size_t)(r0 + tr) * 256 + c0 + tc;
    f32x4 v = *(const f32x4*)p;
    for (int s = 1; s < S; ++s) v += *(const f32x4*)(p + (long long)s * ldS);
    if (h) v *= h[((size_t)b * 8 + ((c0 + tc) >> 5)) * P + r0 + tr];
    u16x4 hh = {f2bf(v[0]), f2bf(v[1]), f2bf(v[2]), f2bf(v[3])};
    *(u16x4*)&thi[tr][tc] = hh;
    if (out_lo) {
      u16x4 ll = {f2bf(v[0] - bf2f(hh[0])), f2bf(v[1] - bf2f(hh[1])),
                  f2bf(v[2] - bf2f(hh[2])), f2bf(v[3] - bf2f(hh[3]))};
      *(u16x4*)&tlo[tr][tc] = ll;
    }
  }
  __syncthreads();
  #pragma unroll
  for (int a = 0; a < 2; ++a) {
    int idx = t + 256 * a;          // 0..511 : 64 channels x 8 pos-octets
    int orow = idx >> 3, oc = (idx & 7) * 8;
    u16x8 vh;
    #pragma unroll
    for (int j = 0; j < 8; ++j) vh[j] = thi[oc + j][orow];
    *(u16x8*)(out_hi + ((size_t)b * 256 + c0 + orow) * P + r0 + oc) = vh;
    if (out_lo) {
      u16x8 vl;
      #pragma unroll
      for (int j = 0; j < 8; ++j) vl[j] = tlo[oc + j][orow];
      *(u16x8*)(out_lo + ((size_t)b * 256 + c0 + orow) * P + r0 + oc) = vl;
    }
  }
}

// ---------------------------------------------------------------------------
// v-pair hval replicating numpy fp32 arithmetic (validated round 3).
// ---------------------------------------------------------------------------
__global__ __launch_bounds__(256) void vproj_hval_np(
    const float* __restrict__ X, const float* __restrict__ Wq,
    const float* __restrict__ Wk, float* __restrict__ hout, int P) {
  __shared__ float sx[256];
  __shared__ float sq[256], sk[256];
  const int row = blockIdx.x;
  const int j = threadIdx.x;
  sx[j] = X[(size_t)row * 256 + j];
  __syncthreads();
  float q = 0.0f, k = 0.0f;
  for (int i = 0; i < 256; ++i) {
    float xi = sx[i];
    q = __fmaf_rn(xi, Wq[i * 256 + j], q);
    k = __fmaf_rn(xi, Wk[i * 256 + j], k);
  }
  sq[j] = q;
  sk[j] = k;
  __syncthreads();
  if (j < 8) {
    const float* qq = &sq[j * 32];
    const float* kk = &sk[j * 32];
    float s0 = 0.0f, s1 = 0.0f, s2 = 0.0f, s3 = 0.0f;
    #pragma unroll 1
    for (int d = 0; d < 32; d += 4) {
      s0 = __fadd_rn(s0, __fmul_rn(qq[d + 0], kk[d + 0]));
      s1 = __fadd_rn(s1, __fmul_rn(qq[d + 1], kk[d + 1]));
      s2 = __fadd_rn(s2, __fmul_rn(qq[d + 2], kk[d + 2]));
      s3 = __fadd_rn(s3, __fmul_rn(qq[d + 3], kk[d + 3]));
    }
    float p = __fadd_rn(__fadd_rn(s0, s2), __fadd_rn(s1, s3));
    float hval = __fdiv_rn(p, sqrtf(32.0f));
    float inv = __fdiv_rn(1.0f, __fadd_rn(hval, 1e-6f));
    const int b = row / P, pos = row - b * P;
    hout[((size_t)b * 8 + j) * P + pos] = inv;
  }
}

// hval = rowwise per-head dot of fp32 Q,K. One wave per row.
__global__ __launch_bounds__(256) void dot_hval(
    const float* __restrict__ Q, const float* __restrict__ K,
    float* __restrict__ hout, int P) {
  const int wv = threadIdx.x >> 6, lane = threadIdx.x & 63;
  const int row = blockIdx.x * 4 + wv;
  f32x4 q = *(const f32x4*)(Q + (size_t)row * 256 + lane * 4);
  f32x4 k = *(const f32x4*)(K + (size_t)row * 256 + lane * 4);
  float p = q[0] * k[0] + q[1] * k[1] + q[2] * k[2] + q[3] * k[3];
  p += __shfl_xor(p, 1);
  p += __shfl_xor(p, 2);
  p += __shfl_xor(p, 4);
  if ((lane & 7) == 0) {
    const int head = lane >> 3;
    const int b = row / P, pos = row % P;
    hout[((size_t)b * 8 + head) * P + pos] = p * 0.17677669529663687f;
  }
}

// Sf = (T4p0 + T4p1) + (T2p0 + T2p1) * einv_hval     (fp32, [12288][256])
__global__ void combine_S(const float* __restrict__ T2p,
                          const float* __restrict__ T4p,
                          const float* __restrict__ h,
                          float* __restrict__ Sf) {
  const long long nq = 12288LL * 64;
  const long long slab = 6144LL * 64;  // f32x4 per (batch,split) slab
  long long i = (long long)blockIdx.x * blockDim.x + threadIdx.x;
  const long long stride = (long long)gridDim.x * blockDim.x;
  for (; i < nq; i += stride) {
    long long rr = i >> 6;
    int b = rr >= 6144;
    long long pos = rr - (long long)b * 6144;
    int head = ((int)i & 63) >> 3;
    float s = h[((size_t)b * 8 + head) * 6144 + pos];
    long long iw = i - (long long)b * slab;
    const f32x4* t2a = (const f32x4*)T2p + (long long)(b * 2) * slab;
    const f32x4* t4a = (const f32x4*)T4p + (long long)(b * 2) * slab;
    f32x4 t2 = t2a[iw] + t2a[iw + slab];
    f32x4 t4 = t4a[iw] + t4a[iw + slab];
    ((f32x4*)Sf)[i] = t4 + t2 * s;
  }
}

// ---------------------------------------------------------------------------
extern "C" void kernel_launch(void* const* d_in, const int* in_sizes, int n_in,
                              void* d_out, int out_size, void* d_ws, size_t ws_size,
                              hipStream_t stream) {
  const float* x_v = (const float*)d_in[0];
  const float* x_e = (const float*)d_in[1];
  const float* x_f = (const float*)d_in[2];
  const float* d0  = (const float*)d_in[3];   // (2, 6144, 2048)
  const float* d1  = (const float*)d_in[4];   // (2, 4096, 6144)
  const float* W_vq    = (const float*)d_in[5];
  const float* W_vk    = (const float*)d_in[6];
  const float* Wsrc[8] = {(const float*)d_in[7],  (const float*)d_in[8],    // eq, ek
                          (const float*)d_in[9],  (const float*)d_in[10],   // einvq, einvk
                          (const float*)d_in[12], (const float*)d_in[13],   // fq, fk
                          (const float*)d_in[11], (const float*)d_in[14]};  // ev, o
  const int loIdx[8] = {0, 1, -1, -1, -1, -1, 2, 3};
  float* out = (float*)d_out;

  const int NV = 2048, ME = 6144, KF = 4096;

  char* ws = (char*)d_ws;
  size_t o = 0;
  auto alloc = [&](size_t bytes) { size_t r = o; o = (o + bytes + 255) & ~255ULL; return r; };

  unsigned short* WT_hi = (unsigned short*)(ws + alloc(8 * 65536 * 2));
  unsigned short* WT_lo = (unsigned short*)(ws + alloc(4 * 65536 * 2));
  float* pHvE  = (float*)(ws + alloc(2 * 8 * ME * 4));
  float* pHvEi = (float*)(ws + alloc(2 * 8 * ME * 4));
  float* pHvF  = (float*)(ws + alloc(2 * 8 * KF * 4));
  float* pHvV  = (float*)(ws + alloc(2 * 8 * NV * 4));
  unsigned short* eVT_hi = (unsigned short*)(ws + alloc((size_t)2 * 256 * ME * 2));
  unsigned short* Y0T_hi = (unsigned short*)(ws + alloc((size_t)2 * 256 * ME * 2));
  unsigned short* Y0T_lo = (unsigned short*)(ws + alloc((size_t)2 * 256 * ME * 2));
  unsigned short* T1sT_hi = (unsigned short*)(ws + alloc((size_t)2 * 256 * KF * 2));
  unsigned short* T3sT_hi = (unsigned short*)(ws + alloc((size_t)2 * 256 * NV * 2));
  unsigned short* T3sT_lo = (unsigned short*)(ws + alloc((size_t)2 * 256 * NV * 2));
  float* slabP  = (float*)(ws + alloc((size_t)2 * 3 * 4096 * 256 * 4));  // T1p -> T3p -> T4p
  float* slabQK = (float*)(ws + alloc((size_t)2 * 12288 * 256 * 4));     // Q,K -> T2p
  float* slabEV = (float*)(ws + alloc((size_t)12288 * 256 * 4));         // eVf -> Sf

  float* pQ = slabQK;
  float* pK = slabQK + (size_t)12288 * 256;
  float* pT2p = slabQK;
  float* pEVf = slabEV;
  float* pSf  = slabEV;
  float* pT1p = slabP;
  float* pT3p = slabP;
  float* pT4p = slabP;

  dim3 blk(256);
  const long long sQK = 12288LL * 256;

  // --- weight transposes (bf16 [n][k]) ---
  for (int w = 0; w < 8; ++w)
    xpose_cvt<<<dim3(4, 4, 1), blk, 0, stream>>>(
        Wsrc[w], WT_hi + (size_t)w * 65536,
        loIdx[w] >= 0 ? WT_lo + (size_t)loIdx[w] * 65536 : nullptr,
        nullptr, 1, 0, 0, 256);

  // --- v hval (np-fp32 exact) ---
  vproj_hval_np<<<2 * NV, blk, 0, stream>>>(x_v, W_vq, W_vk, pHvV, NV);

  // --- e / einv / f hval pairs (pair via grid.z=2) ---
  gemm_ws<false, true><<<dim3(96, 2, 2), blk, 0, stream>>>(
      x_e, WT_hi + 0, WT_lo + 0, pQ, 256, 256, 1, 0, 65536, sQK);
  dot_hval<<<12288 / 4, blk, 0, stream>>>(pQ, pK, pHvE, ME);
  gemm_ws<false, false><<<dim3(96, 2, 2), blk, 0, stream>>>(
      x_e, WT_hi + 2 * 65536, nullptr, pQ, 256, 256, 1, 0, 65536, sQK);
  dot_hval<<<12288 / 4, blk, 0, stream>>>(pQ, pK, pHvEi, ME);
  gemm_ws<false, false><<<dim3(64, 2, 2), blk, 0, stream>>>(
      x_f, WT_hi + 4 * 65536, nullptr, pQ, 256, 256, 1, 0, 65536, sQK);
  dot_hval<<<8192 / 4, blk, 0, stream>>>(pQ, pK, pHvF, KF);

  // --- eV projection (split) + transposed bf16 forms ---
  gemm_ws<false, true><<<dim3(96, 2, 1), blk, 0, stream>>>(
      x_e, WT_hi + 6 * 65536, WT_lo + 2 * 65536, pEVf, 256, 256, 1, 0, 0, 0);
  xpose_cvt<<<dim3(96, 4, 2), blk, 0, stream>>>(
      pEVf, eVT_hi, nullptr, nullptr, 1, 0, (long long)ME * 256, ME);
  xpose_cvt<<<dim3(96, 4, 2), blk, 0, stream>>>(
      pEVf, Y0T_hi, Y0T_lo, pHvE, 1, 0, (long long)ME * 256, ME);

  // --- up branch: T1 = d1 @ eV (plain, S=3) ; T1s ; T2 = d1^T @ T1s (plain, S=2)
  gemm_ws<false, false><<<dim3(32, 2, 6), blk, 0, stream>>>(
      d1, eVT_hi, nullptr, pT1p, ME, ME, 3, (long long)KF * ME, 256LL * ME, (long long)KF * 256);
  xpose_cvt<<<dim3(64, 4, 2), blk, 0, stream>>>(
      pT1p, T1sT_hi, nullptr, pHvF, 3, (long long)KF * 256, 3LL * KF * 256, KF);
  gemm_ws<true, false><<<dim3(48, 2, 4), blk, 0, stream>>>(
      d1, T1sT_hi, nullptr, pT2p, KF, ME, 2, (long long)KF * ME, 256LL * KF, (long long)ME * 256);

  // --- down branch: T3 = d0^T @ Y0 (split, S=6) ; T3s ; T4 = d0 @ T3s (split, S=2)
  gemm_ws<true, true><<<dim3(16, 2, 12), blk, 0, stream>>>(
      d0, Y0T_hi, Y0T_lo, pT3p, ME, NV, 6, (long long)ME * NV, 256LL * ME, (long long)NV * 256);
  xpose_cvt<<<dim3(32, 4, 2), blk, 0, stream>>>(
      pT3p, T3sT_hi, T3sT_lo, pHvV, 6, (long long)NV * 256, 6LL * NV * 256, NV);
  gemm_ws<false, true><<<dim3(48, 2, 4), blk, 0, stream>>>(
      d0, T3sT_hi, T3sT_lo, pT4p, NV, NV, 2, (long long)ME * NV, 256LL * NV, (long long)ME * 256);

  // --- combine + output projection (split) ---
  combine_S<<<3072, blk, 0, stream>>>(pT2p, pT4p, pHvEi, pSf);
  gemm_ws<false, true><<<dim3(96, 2, 1), blk, 0, stream>>>(
      pSf, WT_hi + 7 * 65536, WT_lo + 3 * 65536, out, 256, 256, 1, 0, 0, 0);
}

// Round 5
// 629.805 us; speedup vs baseline: 2.0870x; 1.2183x over previous
//
#include <hip/hip_runtime.h>
#include <hip/hip_bf16.h>
#include <cstdint>
#include <cstddef>

// ---------------------------------------------------------------------------
// MeshMultiHeadHodgeLaplaceAttention  (b=2, n=2048, m=6144, k=4096, D=256, H=8)
//
//   up:   T1 = d_1 @ eV ; *f_hval ; T2 = d_1^T @ T1s ; (*einv_hval in combine)
//   down: Y0 = eV*e_hval ; T3 = d_0^T @ Y0 ; *1/(v_hval+eps) ; T4 = d_0 @ T3s
//   out = (T2*einv_hval + T4) @ W_o
//
// Precision (validated R3/R4): v_hval replicates numpy fp32 bit-exactly;
// amplified chain {eq/ek, eV, T3, T4, out} split-bf16 (hi/lo, 3 MFMA passes);
// rest plain bf16.
//
// R5 structure: no transposed staging inside GEMMs. d0/d1 pre-transposed to
// bf16 once (LDS-tiled); T3 role-swapped (T3^T = Y0^T @ d0) so its output is
// directly the next B operand; concat-N projection GEMMs; all staging u16x8.
// ---------------------------------------------------------------------------

typedef __attribute__((ext_vector_type(4))) float f32x4;
typedef __attribute__((ext_vector_type(4))) unsigned short u16x4;
typedef __attribute__((ext_vector_type(8))) unsigned short u16x8;
typedef __attribute__((ext_vector_type(8))) __bf16 bf16x8;

static __device__ __forceinline__ unsigned short f2bf(float f) {
  uint32_t u = __builtin_bit_cast(uint32_t, f);
  uint32_t r = (u + 0x7FFFu + ((u >> 16) & 1u)) >> 16;  // RNE
  return (unsigned short)r;
}
static __device__ __forceinline__ float bf2f(unsigned short h) {
  return __builtin_bit_cast(float, (uint32_t)h << 16);
}

// ---------------------------------------------------------------------------
// GEMM: C[M x NC] = A[M x K] * B, NC = gridDim.y*128.
// A: fp32 [M][K] (cvt in staging) if !ABF, else bf16 hi(/lo) [M][K].
// B: bf16 hi(/lo), pre-transposed [N][K].
// Split-K: blockIdx.z = batch*S + split, each split writes its own C slab.
// 128x128 tile, BK=32, 4 waves 2x2, each 4x4 16x16x32 frags.
// ---------------------------------------------------------------------------
template <bool ABF, bool SPLIT>
__global__ __launch_bounds__(256) void gemm_ws(
    const float* __restrict__ Af, const unsigned short* __restrict__ Ah,
    const unsigned short* __restrict__ Al,
    const unsigned short* __restrict__ Bh, const unsigned short* __restrict__ Bl,
    float* __restrict__ C, int K, int ldA, int S,
    long long sA, long long sB, long long sC) {
  const int z = blockIdx.z;
  const int batch = z / S, split = z - batch * S;
  if constexpr (ABF) {
    Ah += (long long)batch * sA;
    if constexpr (SPLIT) Al += (long long)batch * sA;
  } else {
    Af += (long long)batch * sA;
  }
  Bh += (long long)batch * sB;
  if constexpr (SPLIT) Bl += (long long)batch * sB;
  C += (long long)z * sC;

  // XCD-bijective swizzle; decode with y fastest (same-A blocks adjacent).
  const int gx = gridDim.x, gy = gridDim.y;
  const int nwg = gx * gy;
  const int wid = blockIdx.x + gx * blockIdx.y;
  const int q = nwg >> 3, r = nwg & 7;
  const int xcd = wid & 7, posn = wid >> 3;
  const int swz = (xcd < r ? xcd * (q + 1) : r * (q + 1) + (xcd - r) * q) + posn;
  const int mt = swz / gy;
  const int m0 = mt * 128, n0 = (swz - mt * gy) * 128;
  const int NC = gy << 7;

  const int kLen = K / S, k0base = split * kLen;
  constexpr int NBUF = SPLIT ? 4 : 2;
  __shared__ unsigned short lds[NBUF][128][40];  // [0]=Ah [1]=Bh [2]=Al [3]=Bl

  const int t = threadIdx.x;
  const int wid4 = t >> 6, lane = t & 63;
  const int wr = wid4 >> 1, wc = wid4 & 1;
  const int lr = lane & 15, kq = lane >> 4;

  f32x4 acc[4][4] = {};

  for (int kk = 0; kk < kLen; kk += 32) {
    const int kb = k0base + kk;
    // ---- stage A ----
    if constexpr (!ABF) {
      #pragma unroll
      for (int a = 0; a < 4; ++a) {
        int idx = t + 256 * a;                 // 128 rows x 8 f32x4
        int row = idx >> 3, qd = (idx & 7) * 4;
        f32x4 v = *(const f32x4*)(Af + (size_t)(m0 + row) * ldA + kb + qd);
        u16x4 h = {f2bf(v[0]), f2bf(v[1]), f2bf(v[2]), f2bf(v[3])};
        *(u16x4*)&lds[0][row][qd] = h;
        if constexpr (SPLIT) {
          u16x4 l = {f2bf(v[0] - bf2f(h[0])), f2bf(v[1] - bf2f(h[1])),
                     f2bf(v[2] - bf2f(h[2])), f2bf(v[3] - bf2f(h[3]))};
          *(u16x4*)&lds[2][row][qd] = l;
        }
      }
    } else {
      #pragma unroll
      for (int a = 0; a < 2; ++a) {
        int idx = t + 256 * a;                 // 128 rows x 4 u16x8
        int row = idx >> 2, c8 = (idx & 3) * 8;
        *(u16x8*)&lds[0][row][c8] = *(const u16x8*)(Ah + (size_t)(m0 + row) * ldA + kb + c8);
        if constexpr (SPLIT)
          *(u16x8*)&lds[2][row][c8] = *(const u16x8*)(Al + (size_t)(m0 + row) * ldA + kb + c8);
      }
    }
    // ---- stage B (pre-transposed [n][K]) ----
    #pragma unroll
    for (int a = 0; a < 2; ++a) {
      int idx = t + 256 * a;
      int row = idx >> 2, c8 = (idx & 3) * 8;
      *(u16x8*)&lds[1][row][c8] = *(const u16x8*)(Bh + (size_t)(n0 + row) * K + kb + c8);
      if constexpr (SPLIT)
        *(u16x8*)&lds[3][row][c8] = *(const u16x8*)(Bl + (size_t)(n0 + row) * K + kb + c8);
    }
    __syncthreads();

    bf16x8 ah[4], bh[4], al[4], bl[4];
    #pragma unroll
    for (int i = 0; i < 4; ++i) {
      ah[i] = __builtin_bit_cast(bf16x8, *(const u16x8*)&lds[0][wr * 64 + i * 16 + lr][kq * 8]);
      bh[i] = __builtin_bit_cast(bf16x8, *(const u16x8*)&lds[1][wc * 64 + i * 16 + lr][kq * 8]);
      if constexpr (SPLIT) {
        al[i] = __builtin_bit_cast(bf16x8, *(const u16x8*)&lds[2][wr * 64 + i * 16 + lr][kq * 8]);
        bl[i] = __builtin_bit_cast(bf16x8, *(const u16x8*)&lds[3][wc * 64 + i * 16 + lr][kq * 8]);
      }
    }
    #pragma unroll
    for (int i = 0; i < 4; ++i)
      #pragma unroll
      for (int j = 0; j < 4; ++j) {
        acc[i][j] = __builtin_amdgcn_mfma_f32_16x16x32_bf16(ah[i], bh[j], acc[i][j], 0, 0, 0);
        if constexpr (SPLIT) {
          acc[i][j] = __builtin_amdgcn_mfma_f32_16x16x32_bf16(ah[i], bl[j], acc[i][j], 0, 0, 0);
          acc[i][j] = __builtin_amdgcn_mfma_f32_16x16x32_bf16(al[i], bh[j], acc[i][j], 0, 0, 0);
        }
      }
    __syncthreads();
  }

  // epilogue: D mapping col = lane&15, row = (lane>>4)*4 + q
  #pragma unroll
  for (int i = 0; i < 4; ++i)
    #pragma unroll
    for (int j = 0; j < 4; ++j) {
      float* cp = C + (size_t)(m0 + wr * 64 + i * 16 + kq * 4) * NC + n0 + wc * 64 + j * 16 + lr;
      #pragma unroll
      for (int qq = 0; qq < 4; ++qq) cp[(size_t)qq * NC] = acc[i][j][qq];
    }
}

// ---------------------------------------------------------------------------
// xpose_cvt: in fp32 [NB][S][rows][ldIn] -> out bf16 [NB][outR=cols][P=rows]
// (sum S slabs ascending, optional per-(row,head) scale). 64x64 LDS tile.
// ---------------------------------------------------------------------------
__global__ __launch_bounds__(256) void xpose_cvt(
    const float* __restrict__ in, unsigned short* __restrict__ out_hi,
    unsigned short* __restrict__ out_lo, const float* __restrict__ h,
    int S, long long ldS, long long inB, int P, int ldIn, int outR) {
  __shared__ unsigned short thi[64][72], tlo[64][72];
  const int b = blockIdx.z;
  const int r0 = blockIdx.x * 64;   // in-row (= out col)
  const int c0 = blockIdx.y * 64;   // in-col (= out row)
  const float* src = in + (long long)b * inB;
  const int t = threadIdx.x;
  #pragma unroll
  for (int a = 0; a < 4; ++a) {
    int idx = t + 256 * a;
    int tr = idx >> 4, tc = (idx & 15) * 4;
    const float* p = src + (size_t)(r0 + tr) * ldIn + c0 + tc;
    f32x4 v = *(const f32x4*)p;
    for (int s = 1; s < S; ++s) v += *(const f32x4*)(p + (long long)s * ldS);
    if (h) v *= h[((size_t)b * 8 + ((c0 + tc) >> 5)) * P + r0 + tr];
    u16x4 hh = {f2bf(v[0]), f2bf(v[1]), f2bf(v[2]), f2bf(v[3])};
    *(u16x4*)&thi[tr][tc] = hh;
    if (out_lo) {
      u16x4 ll = {f2bf(v[0] - bf2f(hh[0])), f2bf(v[1] - bf2f(hh[1])),
                  f2bf(v[2] - bf2f(hh[2])), f2bf(v[3] - bf2f(hh[3]))};
      *(u16x4*)&tlo[tr][tc] = ll;
    }
  }
  __syncthreads();
  #pragma unroll
  for (int a = 0; a < 2; ++a) {
    int idx = t + 256 * a;
    int orow = idx >> 3, oc = (idx & 7) * 8;
    u16x8 vh;
    #pragma unroll
    for (int j = 0; j < 8; ++j) vh[j] = thi[oc + j][orow];
    *(u16x8*)(out_hi + ((size_t)b * outR + c0 + orow) * P + r0 + oc) = vh;
    if (out_lo) {
      u16x8 vl;
      #pragma unroll
      for (int j = 0; j < 8; ++j) vl[j] = tlo[oc + j][orow];
      *(u16x8*)(out_lo + ((size_t)b * outR + c0 + orow) * P + r0 + oc) = vl;
    }
  }
}

// ---------------------------------------------------------------------------
// rsc_cvt: in fp32 [2][S][R][P] -> out bf16 hi(+lo) [2][R][P], sum S slabs
// (ascending), scale by h[b][row>>5][pos]. Pure elementwise (no transpose).
// ---------------------------------------------------------------------------
__global__ void rsc_cvt(const float* __restrict__ in,
                        unsigned short* __restrict__ out_hi,
                        unsigned short* __restrict__ out_lo,
                        const float* __restrict__ h, int S, int R, int P) {
  const long long qP = P >> 2;
  const long long nq = 2LL * R * qP;
  long long i = (long long)blockIdx.x * blockDim.x + threadIdx.x;
  const long long stride = (long long)gridDim.x * blockDim.x;
  for (; i < nq; i += stride) {
    long long b = i / (R * qP);
    long long rem = i - b * (R * qP);
    int row = (int)(rem / qP);
    long long qc = rem - (long long)row * qP;
    const f32x4* base = (const f32x4*)in + ((b * S) * R + row) * qP + qc;
    f32x4 v = base[0];
    for (int s = 1; s < S; ++s) v += base[(long long)s * R * qP];
    v *= *(const f32x4*)(h + ((size_t)b * 8 + (row >> 5)) * P + (qc << 2));
    u16x4 hh = {f2bf(v[0]), f2bf(v[1]), f2bf(v[2]), f2bf(v[3])};
    ((u16x4*)out_hi)[i] = hh;
    if (out_lo) {
      u16x4 ll = {f2bf(v[0] - bf2f(hh[0])), f2bf(v[1] - bf2f(hh[1])),
                  f2bf(v[2] - bf2f(hh[2])), f2bf(v[3] - bf2f(hh[3]))};
      ((u16x4*)out_lo)[i] = ll;
    }
  }
}

// ---------------------------------------------------------------------------
// v-pair hval, numpy-fp32-exact (validated R3). 8 rows per block.
// ---------------------------------------------------------------------------
__global__ __launch_bounds__(256) void vproj_hval_np(
    const float* __restrict__ X, const float* __restrict__ Wq,
    const float* __restrict__ Wk, float* __restrict__ hout, int P) {
  __shared__ float sx[8][256], sq[8][256], sk[8][256];
  const int r0 = blockIdx.x * 8;
  const int j = threadIdx.x;
  #pragma unroll
  for (int r = 0; r < 8; ++r) sx[r][j] = X[(size_t)(r0 + r) * 256 + j];
  __syncthreads();
  float qa[8] = {}, ka[8] = {};
  for (int i = 0; i < 256; ++i) {
    float wq = Wq[i * 256 + j], wk = Wk[i * 256 + j];
    #pragma unroll
    for (int r = 0; r < 8; ++r) {
      qa[r] = __fmaf_rn(sx[r][i], wq, qa[r]);
      ka[r] = __fmaf_rn(sx[r][i], wk, ka[r]);
    }
  }
  #pragma unroll
  for (int r = 0; r < 8; ++r) { sq[r][j] = qa[r]; sk[r][j] = ka[r]; }
  __syncthreads();
  if (j < 64) {
    const int r = j >> 3, head = j & 7;
    const float* qq = &sq[r][head * 32];
    const float* kk = &sk[r][head * 32];
    float s0 = 0.0f, s1 = 0.0f, s2 = 0.0f, s3 = 0.0f;
    #pragma unroll 1
    for (int d = 0; d < 32; d += 4) {
      s0 = __fadd_rn(s0, __fmul_rn(qq[d + 0], kk[d + 0]));
      s1 = __fadd_rn(s1, __fmul_rn(qq[d + 1], kk[d + 1]));
      s2 = __fadd_rn(s2, __fmul_rn(qq[d + 2], kk[d + 2]));
      s3 = __fadd_rn(s3, __fmul_rn(qq[d + 3], kk[d + 3]));
    }
    float p = __fadd_rn(__fadd_rn(s0, s2), __fadd_rn(s1, s3));
    float hval = __fdiv_rn(p, sqrtf(32.0f));
    float inv = __fdiv_rn(1.0f, __fadd_rn(hval, 1e-6f));
    const int row = r0 + r;
    const int b = row / P, pos = row - b * P;
    hout[((size_t)b * 8 + head) * P + pos] = inv;
  }
}

// hval = rowwise per-head dot of fp32 Q,K (ld = row stride). One wave/row.
__global__ __launch_bounds__(256) void dot_hval(
    const float* __restrict__ Q, const float* __restrict__ K,
    float* __restrict__ hout, int P, int ld) {
  const int wv = threadIdx.x >> 6, lane = threadIdx.x & 63;
  const int row = blockIdx.x * 4 + wv;
  f32x4 q = *(const f32x4*)(Q + (size_t)row * ld + lane * 4);
  f32x4 k = *(const f32x4*)(K + (size_t)row * ld + lane * 4);
  float p = q[0] * k[0] + q[1] * k[1] + q[2] * k[2] + q[3] * k[3];
  p += __shfl_xor(p, 1);
  p += __shfl_xor(p, 2);
  p += __shfl_xor(p, 4);
  if ((lane & 7) == 0) {
    const int head = lane >> 3;
    const int b = row / P, pos = row % P;
    hout[((size_t)b * 8 + head) * P + pos] = p * 0.17677669529663687f;
  }
}

// Sf = (T4p0+T4p1) + (T2p0+T2p1)*einv_hval   ([2][2][6144][256] slabs each)
__global__ void combine_S(const float* __restrict__ T2p,
                          const float* __restrict__ T4p,
                          const float* __restrict__ h,
                          float* __restrict__ Sf) {
  const long long nq = 12288LL * 64;
  const long long slab = 6144LL * 64;
  long long i = (long long)blockIdx.x * blockDim.x + threadIdx.x;
  const long long stride = (long long)gridDim.x * blockDim.x;
  for (; i < nq; i += stride) {
    long long rr = i >> 6;
    int b = rr >= 6144;
    long long pos = rr - (long long)b * 6144;
    int head = ((int)i & 63) >> 3;
    float s = h[((size_t)b * 8 + head) * 6144 + pos];
    long long iw = i - (long long)b * slab;
    const f32x4* t2a = (const f32x4*)T2p + (long long)(b * 2) * slab;
    const f32x4* t4a = (const f32x4*)T4p + (long long)(b * 2) * slab;
    f32x4 t2 = t2a[iw] + t2a[iw + slab];
    f32x4 t4 = t4a[iw] + t4a[iw + slab];
    ((f32x4*)Sf)[i] = t4 + t2 * s;
  }
}

// ---------------------------------------------------------------------------
extern "C" void kernel_launch(void* const* d_in, const int* in_sizes, int n_in,
                              void* d_out, int out_size, void* d_ws, size_t ws_size,
                              hipStream_t stream) {
  const float* x_v = (const float*)d_in[0];
  const float* x_e = (const float*)d_in[1];
  const float* x_f = (const float*)d_in[2];
  const float* d0  = (const float*)d_in[3];   // (2, 6144, 2048)
  const float* d1  = (const float*)d_in[4];   // (2, 4096, 6144)
  const float* W_vq    = (const float*)d_in[5];
  const float* W_vk    = (const float*)d_in[6];
  const float* W_eq    = (const float*)d_in[7];
  const float* W_ek    = (const float*)d_in[8];
  const float* W_einvq = (const float*)d_in[9];
  const float* W_einvk = (const float*)d_in[10];
  const float* W_ev    = (const float*)d_in[11];
  const float* W_fq    = (const float*)d_in[12];
  const float* W_fk    = (const float*)d_in[13];
  const float* W_o     = (const float*)d_in[14];
  float* out = (float*)d_out;

  const int NV = 2048, ME = 6144, KF = 4096;
  const unsigned short* NUS = nullptr;

  char* ws = (char*)d_ws;
  size_t o = 0;
  auto alloc = [&](size_t bytes) { size_t r = o; o = (o + bytes + 255) & ~255ULL; return r; };

  unsigned short* WcatE_hi = (unsigned short*)(ws + alloc(768 * 256 * 2));
  unsigned short* WcatE_lo = (unsigned short*)(ws + alloc(768 * 256 * 2));
  unsigned short* W2_hi = (unsigned short*)(ws + alloc(512 * 256 * 2));
  unsigned short* W3_hi = (unsigned short*)(ws + alloc(512 * 256 * 2));
  unsigned short* Wo_hi = (unsigned short*)(ws + alloc(256 * 256 * 2));
  unsigned short* Wo_lo = (unsigned short*)(ws + alloc(256 * 256 * 2));
  float* pHvE  = (float*)(ws + alloc(2 * 8 * ME * 4));
  float* pHvEi = (float*)(ws + alloc(2 * 8 * ME * 4));
  float* pHvF  = (float*)(ws + alloc(2 * 8 * KF * 4));
  float* pHvV  = (float*)(ws + alloc(2 * 8 * NV * 4));
  unsigned short* d1T_hi = (unsigned short*)(ws + alloc((size_t)2 * ME * KF * 2));   // [2][6144][4096]
  unsigned short* d0T_hi = (unsigned short*)(ws + alloc((size_t)2 * NV * ME * 2));   // [2][2048][6144]
  unsigned short* d0T_lo = (unsigned short*)(ws + alloc((size_t)2 * NV * ME * 2));
  unsigned short* eVT_hi = (unsigned short*)(ws + alloc((size_t)2 * 256 * ME * 2));  // [2][256][6144]
  unsigned short* Y0T_hi = (unsigned short*)(ws + alloc((size_t)2 * 256 * ME * 2));
  unsigned short* Y0T_lo = (unsigned short*)(ws + alloc((size_t)2 * 256 * ME * 2));
  unsigned short* T1sT_hi = (unsigned short*)(ws + alloc((size_t)2 * 256 * KF * 2)); // [2][256][4096]
  unsigned short* T3sT_hi = (unsigned short*)(ws + alloc((size_t)2 * 256 * NV * 2)); // [2][256][2048]
  unsigned short* T3sT_lo = (unsigned short*)(ws + alloc((size_t)2 * 256 * NV * 2));
  float* pP1 = (float*)(ws + alloc((size_t)12288 * 768 * 4));  // later: T2p [2][2][6144][256]
  float* pP2 = (float*)(ws + alloc((size_t)12288 * 512 * 4));  // later: T4p
  float* pP3 = (float*)(ws + alloc((size_t)8192 * 512 * 4));   // later: Sf
  float* pTp = (float*)(ws + alloc((size_t)2 * 3 * 4096 * 256 * 4));  // T1p / T3p

  float* pT2p = pP1;
  float* pT4p = pP2;
  float* pSf  = pP3;

  dim3 blk(256);

  // --- weight transposes -> bf16 [n][k] ---
  xpose_cvt<<<dim3(4, 4, 1), blk, 0, stream>>>(W_eq, WcatE_hi, WcatE_lo, nullptr, 1, 0, 0, 256, 256, 256);
  xpose_cvt<<<dim3(4, 4, 1), blk, 0, stream>>>(W_ek, WcatE_hi + 65536, WcatE_lo + 65536, nullptr, 1, 0, 0, 256, 256, 256);
  xpose_cvt<<<dim3(4, 4, 1), blk, 0, stream>>>(W_ev, WcatE_hi + 131072, WcatE_lo + 131072, nullptr, 1, 0, 0, 256, 256, 256);
  xpose_cvt<<<dim3(4, 4, 1), blk, 0, stream>>>(W_einvq, W2_hi, nullptr, nullptr, 1, 0, 0, 256, 256, 256);
  xpose_cvt<<<dim3(4, 4, 1), blk, 0, stream>>>(W_einvk, W2_hi + 65536, nullptr, nullptr, 1, 0, 0, 256, 256, 256);
  xpose_cvt<<<dim3(4, 4, 1), blk, 0, stream>>>(W_fq, W3_hi, nullptr, nullptr, 1, 0, 0, 256, 256, 256);
  xpose_cvt<<<dim3(4, 4, 1), blk, 0, stream>>>(W_fk, W3_hi + 65536, nullptr, nullptr, 1, 0, 0, 256, 256, 256);
  xpose_cvt<<<dim3(4, 4, 1), blk, 0, stream>>>(W_o, Wo_hi, Wo_lo, nullptr, 1, 0, 0, 256, 256, 256);

  // --- d-matrix transposes (once) ---
  xpose_cvt<<<dim3(64, 96, 2), blk, 0, stream>>>(d1, d1T_hi, nullptr, nullptr,
      1, 0, (long long)KF * ME, KF, ME, ME);
  xpose_cvt<<<dim3(96, 32, 2), blk, 0, stream>>>(d0, d0T_hi, d0T_lo, nullptr,
      1, 0, (long long)ME * NV, ME, NV, NV);

  // --- v hval (np-fp32 exact) ---
  vproj_hval_np<<<512, blk, 0, stream>>>(x_v, W_vq, W_vk, pHvV, NV);

  // --- projections: P1 = x_e @ [eq|ek|ev] (split), P2 = x_e @ [einvq|einvk],
  //     P3 = x_f @ [fq|fk] ---
  gemm_ws<false, true><<<dim3(96, 6, 1), blk, 0, stream>>>(
      x_e, NUS, NUS, WcatE_hi, WcatE_lo, pP1, 256, 256, 1, 0, 0, 0);
  dot_hval<<<3072, blk, 0, stream>>>(pP1, pP1 + 256, pHvE, ME, 768);
  gemm_ws<false, false><<<dim3(96, 4, 1), blk, 0, stream>>>(
      x_e, NUS, NUS, W2_hi, NUS, pP2, 256, 256, 1, 0, 0, 0);
  dot_hval<<<3072, blk, 0, stream>>>(pP2, pP2 + 256, pHvEi, ME, 512);
  gemm_ws<false, false><<<dim3(64, 4, 1), blk, 0, stream>>>(
      x_f, NUS, NUS, W3_hi, NUS, pP3, 256, 256, 1, 0, 0, 0);
  dot_hval<<<2048, blk, 0, stream>>>(pP3, pP3 + 256, pHvF, KF, 512);

  // --- eVT (bf16) and Y0T = (eV*e_hval) hi/lo, from P1 cols 512..767 ---
  xpose_cvt<<<dim3(96, 4, 2), blk, 0, stream>>>(pP1 + 512, eVT_hi, nullptr, nullptr,
      1, 0, (long long)ME * 768, ME, 768, 256);
  xpose_cvt<<<dim3(96, 4, 2), blk, 0, stream>>>(pP1 + 512, Y0T_hi, Y0T_lo, pHvE,
      1, 0, (long long)ME * 768, ME, 768, 256);

  // --- up branch ---
  // T1 = d1 @ eV (plain, S=3) -> [2][3][4096][256]
  gemm_ws<false, false><<<dim3(32, 2, 6), blk, 0, stream>>>(
      d1, NUS, NUS, eVT_hi, NUS, pTp, ME, ME, 3,
      (long long)KF * ME, 256LL * ME, (long long)KF * 256);
  // T1sT = (sum slabs * f_hval)^T -> bf16 [2][256][4096]
  xpose_cvt<<<dim3(64, 4, 2), blk, 0, stream>>>(pTp, T1sT_hi, nullptr, pHvF,
      3, (long long)KF * 256, 3LL * KF * 256, KF, 256, 256);
  // T2 = d1T @ T1s (plain, S=2) -> [2][2][6144][256]
  gemm_ws<true, false><<<dim3(48, 2, 4), blk, 0, stream>>>(
      nullptr, d1T_hi, NUS, T1sT_hi, NUS, pT2p, KF, KF, 2,
      (long long)ME * KF, 256LL * KF, (long long)ME * 256);

  // --- down branch ---
  // T3^T = Y0^T @ d0 (split, S=6) -> [2][6][256][2048]
  gemm_ws<true, true><<<dim3(2, 16, 12), blk, 0, stream>>>(
      nullptr, Y0T_hi, Y0T_lo, d0T_hi, d0T_lo, pTp, ME, ME, 6,
      256LL * ME, (long long)NV * ME, 256LL * NV);
  // T3sT = sum slabs * v_inv -> bf16 hi/lo [2][256][2048]
  rsc_cvt<<<1024, blk, 0, stream>>>(pTp, T3sT_hi, T3sT_lo, pHvV, 6, 256, NV);
  // T4 = d0 @ T3s (split, S=2) -> [2][2][6144][256]
  gemm_ws<false, true><<<dim3(48, 2, 4), blk, 0, stream>>>(
      d0, NUS, NUS, T3sT_hi, T3sT_lo, pT4p, NV, NV, 2,
      (long long)ME * NV, 256LL * NV, (long long)ME * 256);

  // --- combine + output projection ---
  combine_S<<<3072, blk, 0, stream>>>(pT2p, pT4p, pHvEi, pSf);
  gemm_ws<false, true><<<dim3(96, 2, 1), blk, 0, stream>>>(
      pSf, NUS, NUS, Wo_hi, Wo_lo, out, 256, 256, 1, 0, 0, 0);
}

// Round 6
// 595.493 us; speedup vs baseline: 2.2072x; 1.0576x over previous
//
#include <hip/hip_runtime.h>
#include <hip/hip_bf16.h>
#include <cstdint>
#include <cstddef>

// ---------------------------------------------------------------------------
// MeshMultiHeadHodgeLaplaceAttention  (b=2, n=2048, m=6144, k=4096, D=256, H=8)
//
//   up:   T1 = d_1 @ eV ; *f_hval ; T2 = d_1^T @ T1s ; (*einv_hval in combine)
//   down: Y0 = eV*e_hval ; T3 = d_0^T @ Y0 ; *1/(v_hval+eps) ; T4 = d_0 @ T3s
//   out = (T2*einv_hval + T4) @ W_o
//
// Precision (validated R3-R5): v_hval replicates numpy fp32 bit-exactly;
// amplified chain {eq/ek/eV proj, T3, T4, out} split-bf16 (hi/lo, 3 MFMA);
// rest plain bf16.
//
// R6: split-K to 768 blocks on all big GEMMs; T1 role-swapped (T1^T =
// eVT @ d1-natural-as-B) killing the T1s transpose; combine fused into the
// W_o GEMM staging; batched weight transposes; per-GEMM L2 pairing order.
// ---------------------------------------------------------------------------

typedef __attribute__((ext_vector_type(4))) float f32x4;
typedef __attribute__((ext_vector_type(4))) unsigned short u16x4;
typedef __attribute__((ext_vector_type(8))) unsigned short u16x8;
typedef __attribute__((ext_vector_type(8))) __bf16 bf16x8;

static __device__ __forceinline__ unsigned short f2bf(float f) {
  uint32_t u = __builtin_bit_cast(uint32_t, f);
  uint32_t r = (u + 0x7FFFu + ((u >> 16) & 1u)) >> 16;  // RNE
  return (unsigned short)r;
}
static __device__ __forceinline__ float bf2f(unsigned short h) {
  return __builtin_bit_cast(float, (uint32_t)h << 16);
}

// ---------------------------------------------------------------------------
// GEMM: C[M x NC] = A[M x K] * B, NC = gridDim.y*128.
// A: fp32 [M][K] (cvt in staging) if !ABF, else bf16 hi(/lo) [M][K] (ldA).
// B: bf16 hi(/lo) [N][K] (ldB), or fp32 [N][K] cvt-in-staging if BF32B.
// Split-K: blockIdx.z = batch*S + split; each split writes its own C slab.
// XFAST: m-tile varies fastest in swizzle decode (B-panel L2 pairing).
// 128x128 tile, BK=32, 4 waves 2x2, each 4x4 16x16x32 frags.
// ---------------------------------------------------------------------------
template <bool ABF, bool BF32B, bool SPLIT, bool XFAST>
__global__ __launch_bounds__(256) void gemm_ws(
    const float* __restrict__ Af, const unsigned short* __restrict__ Ah,
    const unsigned short* __restrict__ Al,
    const float* __restrict__ Bf, const unsigned short* __restrict__ Bh,
    const unsigned short* __restrict__ Bl,
    float* __restrict__ C, int K, int ldA, int ldB, int S,
    long long sA, long long sB, long long sC) {
  const int z = blockIdx.z;
  const int batch = z / S, split = z - batch * S;
  if constexpr (ABF) {
    Ah += (long long)batch * sA;
    if constexpr (SPLIT) Al += (long long)batch * sA;
  } else {
    Af += (long long)batch * sA;
  }
  if constexpr (BF32B) {
    Bf += (long long)batch * sB;
  } else {
    Bh += (long long)batch * sB;
    if constexpr (SPLIT) Bl += (long long)batch * sB;
  }
  C += (long long)z * sC;

  // XCD-bijective swizzle
  const int gx = gridDim.x, gy = gridDim.y;
  const int nwg = gx * gy;
  const int wid = blockIdx.x + gx * blockIdx.y;
  const int q = nwg >> 3, r = nwg & 7;
  const int xcd = wid & 7, posn = wid >> 3;
  const int swz = (xcd < r ? xcd * (q + 1) : r * (q + 1) + (xcd - r) * q) + posn;
  int mt, nt;
  if constexpr (XFAST) { mt = swz % gx; nt = swz / gx; }
  else                 { mt = swz / gy; nt = swz - mt * gy; }
  const int m0 = mt * 128, n0 = nt * 128;
  const int NC = gy << 7;

  const int kLen = K / S, k0base = split * kLen;
  constexpr int NBUF = SPLIT ? 4 : 2;
  __shared__ unsigned short lds[NBUF][128][40];  // [0]=Ah [1]=Bh [2]=Al [3]=Bl

  const int t = threadIdx.x;
  const int wid4 = t >> 6, lane = t & 63;
  const int wr = wid4 >> 1, wc = wid4 & 1;
  const int lr = lane & 15, kq = lane >> 4;

  f32x4 acc[4][4] = {};

  for (int kk = 0; kk < kLen; kk += 32) {
    const int kb = k0base + kk;
    // ---- stage A ----
    if constexpr (!ABF) {
      #pragma unroll
      for (int a = 0; a < 4; ++a) {
        int idx = t + 256 * a;                 // 128 rows x 8 f32x4
        int row = idx >> 3, qd = (idx & 7) * 4;
        f32x4 v = *(const f32x4*)(Af + (size_t)(m0 + row) * ldA + kb + qd);
        u16x4 h = {f2bf(v[0]), f2bf(v[1]), f2bf(v[2]), f2bf(v[3])};
        *(u16x4*)&lds[0][row][qd] = h;
        if constexpr (SPLIT) {
          u16x4 l = {f2bf(v[0] - bf2f(h[0])), f2bf(v[1] - bf2f(h[1])),
                     f2bf(v[2] - bf2f(h[2])), f2bf(v[3] - bf2f(h[3]))};
          *(u16x4*)&lds[2][row][qd] = l;
        }
      }
    } else {
      #pragma unroll
      for (int a = 0; a < 2; ++a) {
        int idx = t + 256 * a;                 // 128 rows x 4 u16x8
        int row = idx >> 2, c8 = (idx & 3) * 8;
        *(u16x8*)&lds[0][row][c8] = *(const u16x8*)(Ah + (size_t)(m0 + row) * ldA + kb + c8);
        if constexpr (SPLIT)
          *(u16x8*)&lds[2][row][c8] = *(const u16x8*)(Al + (size_t)(m0 + row) * ldA + kb + c8);
      }
    }
    // ---- stage B ----
    if constexpr (BF32B) {
      #pragma unroll
      for (int a = 0; a < 4; ++a) {
        int idx = t + 256 * a;
        int row = idx >> 3, qd = (idx & 7) * 4;
        f32x4 v = *(const f32x4*)(Bf + (size_t)(n0 + row) * ldB + kb + qd);
        u16x4 h = {f2bf(v[0]), f2bf(v[1]), f2bf(v[2]), f2bf(v[3])};
        *(u16x4*)&lds[1][row][qd] = h;
      }
    } else {
      #pragma unroll
      for (int a = 0; a < 2; ++a) {
        int idx = t + 256 * a;
        int row = idx >> 2, c8 = (idx & 3) * 8;
        *(u16x8*)&lds[1][row][c8] = *(const u16x8*)(Bh + (size_t)(n0 + row) * ldB + kb + c8);
        if constexpr (SPLIT)
          *(u16x8*)&lds[3][row][c8] = *(const u16x8*)(Bl + (size_t)(n0 + row) * ldB + kb + c8);
      }
    }
    __syncthreads();

    bf16x8 ah[4], bh[4], al[4], bl[4];
    #pragma unroll
    for (int i = 0; i < 4; ++i) {
      ah[i] = __builtin_bit_cast(bf16x8, *(const u16x8*)&lds[0][wr * 64 + i * 16 + lr][kq * 8]);
      bh[i] = __builtin_bit_cast(bf16x8, *(const u16x8*)&lds[1][wc * 64 + i * 16 + lr][kq * 8]);
      if constexpr (SPLIT) {
        al[i] = __builtin_bit_cast(bf16x8, *(const u16x8*)&lds[2][wr * 64 + i * 16 + lr][kq * 8]);
        bl[i] = __builtin_bit_cast(bf16x8, *(const u16x8*)&lds[3][wc * 64 + i * 16 + lr][kq * 8]);
      }
    }
    #pragma unroll
    for (int i = 0; i < 4; ++i)
      #pragma unroll
      for (int j = 0; j < 4; ++j) {
        acc[i][j] = __builtin_amdgcn_mfma_f32_16x16x32_bf16(ah[i], bh[j], acc[i][j], 0, 0, 0);
        if constexpr (SPLIT) {
          acc[i][j] = __builtin_amdgcn_mfma_f32_16x16x32_bf16(ah[i], bl[j], acc[i][j], 0, 0, 0);
          acc[i][j] = __builtin_amdgcn_mfma_f32_16x16x32_bf16(al[i], bh[j], acc[i][j], 0, 0, 0);
        }
      }
    __syncthreads();
  }

  // epilogue: D mapping col = lane&15, row = (lane>>4)*4 + q
  #pragma unroll
  for (int i = 0; i < 4; ++i)
    #pragma unroll
    for (int j = 0; j < 4; ++j) {
      float* cp = C + (size_t)(m0 + wr * 64 + i * 16 + kq * 4) * NC + n0 + wc * 64 + j * 16 + lr;
      #pragma unroll
      for (int qq = 0; qq < 4; ++qq) cp[(size_t)qq * NC] = acc[i][j][qq];
    }
}

// ---------------------------------------------------------------------------
// Output GEMM with fused combine: A[r][c] = (T4p sum of 4 slabs) +
// (T2p sum of 4 slabs)*einv_hval[b, c>>5, pos];  C = A @ W_o (split hi/lo).
// M=12288, N=256, K=256.
// ---------------------------------------------------------------------------
__global__ __launch_bounds__(256) void gemm_out(
    const float* __restrict__ T2p, const float* __restrict__ T4p,
    const float* __restrict__ hEi, const unsigned short* __restrict__ Bh,
    const unsigned short* __restrict__ Bl, float* __restrict__ C) {
  const int gx = gridDim.x, gy = gridDim.y;
  const int nwg = gx * gy;
  const int wid = blockIdx.x + gx * blockIdx.y;
  const int q = nwg >> 3, r = nwg & 7;
  const int xcd = wid & 7, posn = wid >> 3;
  const int swz = (xcd < r ? xcd * (q + 1) : r * (q + 1) + (xcd - r) * q) + posn;
  const int mt = swz / gy;
  const int m0 = mt * 128, n0 = (swz - mt * gy) * 128;

  __shared__ unsigned short lds[4][128][40];
  const int t = threadIdx.x;
  const int wid4 = t >> 6, lane = t & 63;
  const int wr = wid4 >> 1, wc = wid4 & 1;
  const int lr = lane & 15, kq = lane >> 4;
  const long long slab = 6144LL * 256;

  f32x4 acc[4][4] = {};

  for (int kb = 0; kb < 256; kb += 32) {
    #pragma unroll
    for (int a = 0; a < 4; ++a) {
      int idx = t + 256 * a;
      int row = idx >> 3, qd = (idx & 7) * 4;
      int rg = m0 + row;
      int b = rg >= 6144;
      int pos = rg - b * 6144;
      int ck = kb + qd;
      float s = hEi[((size_t)b * 8 + (ck >> 5)) * 6144 + pos];
      const float* b2 = T2p + ((long long)(b * 4) * 6144 + pos) * 256 + ck;
      const float* b4 = T4p + ((long long)(b * 4) * 6144 + pos) * 256 + ck;
      f32x4 t2 = (*(const f32x4*)b2 + *(const f32x4*)(b2 + slab)) +
                 (*(const f32x4*)(b2 + 2 * slab) + *(const f32x4*)(b2 + 3 * slab));
      f32x4 t4 = (*(const f32x4*)b4 + *(const f32x4*)(b4 + slab)) +
                 (*(const f32x4*)(b4 + 2 * slab) + *(const f32x4*)(b4 + 3 * slab));
      f32x4 v = t4 + t2 * s;
      u16x4 h = {f2bf(v[0]), f2bf(v[1]), f2bf(v[2]), f2bf(v[3])};
      *(u16x4*)&lds[0][row][qd] = h;
      u16x4 l = {f2bf(v[0] - bf2f(h[0])), f2bf(v[1] - bf2f(h[1])),
                 f2bf(v[2] - bf2f(h[2])), f2bf(v[3] - bf2f(h[3]))};
      *(u16x4*)&lds[2][row][qd] = l;
    }
    #pragma unroll
    for (int a = 0; a < 2; ++a) {
      int idx = t + 256 * a;
      int row = idx >> 2, c8 = (idx & 3) * 8;
      *(u16x8*)&lds[1][row][c8] = *(const u16x8*)(Bh + (size_t)(n0 + row) * 256 + kb + c8);
      *(u16x8*)&lds[3][row][c8] = *(const u16x8*)(Bl + (size_t)(n0 + row) * 256 + kb + c8);
    }
    __syncthreads();

    bf16x8 ah[4], bh[4], al[4], bl[4];
    #pragma unroll
    for (int i = 0; i < 4; ++i) {
      ah[i] = __builtin_bit_cast(bf16x8, *(const u16x8*)&lds[0][wr * 64 + i * 16 + lr][kq * 8]);
      bh[i] = __builtin_bit_cast(bf16x8, *(const u16x8*)&lds[1][wc * 64 + i * 16 + lr][kq * 8]);
      al[i] = __builtin_bit_cast(bf16x8, *(const u16x8*)&lds[2][wr * 64 + i * 16 + lr][kq * 8]);
      bl[i] = __builtin_bit_cast(bf16x8, *(const u16x8*)&lds[3][wc * 64 + i * 16 + lr][kq * 8]);
    }
    #pragma unroll
    for (int i = 0; i < 4; ++i)
      #pragma unroll
      for (int j = 0; j < 4; ++j) {
        acc[i][j] = __builtin_amdgcn_mfma_f32_16x16x32_bf16(ah[i], bh[j], acc[i][j], 0, 0, 0);
        acc[i][j] = __builtin_amdgcn_mfma_f32_16x16x32_bf16(ah[i], bl[j], acc[i][j], 0, 0, 0);
        acc[i][j] = __builtin_amdgcn_mfma_f32_16x16x32_bf16(al[i], bh[j], acc[i][j], 0, 0, 0);
      }
    __syncthreads();
  }

  #pragma unroll
  for (int i = 0; i < 4; ++i)
    #pragma unroll
    for (int j = 0; j < 4; ++j) {
      float* cp = C + (size_t)(m0 + wr * 64 + i * 16 + kq * 4) * 256 + n0 + wc * 64 + j * 16 + lr;
      #pragma unroll
      for (int qq = 0; qq < 4; ++qq) cp[(size_t)qq * 256] = acc[i][j][qq];
    }
}

// ---------------------------------------------------------------------------
// xpose_cvt: in fp32 [NB][rows][ldIn] -> out bf16 [NB][cols][P=rows] hi(+lo).
// ---------------------------------------------------------------------------
__global__ __launch_bounds__(256) void xpose_cvt(
    const float* __restrict__ in, unsigned short* __restrict__ out_hi,
    unsigned short* __restrict__ out_lo, long long inB, int P, int ldIn, int outR) {
  __shared__ unsigned short thi[64][72], tlo[64][72];
  const int b = blockIdx.z;
  const int r0 = blockIdx.x * 64, c0 = blockIdx.y * 64;
  const float* src = in + (long long)b * inB;
  const int t = threadIdx.x;
  #pragma unroll
  for (int a = 0; a < 4; ++a) {
    int idx = t + 256 * a;
    int tr = idx >> 4, tc = (idx & 15) * 4;
    f32x4 v = *(const f32x4*)(src + (size_t)(r0 + tr) * ldIn + c0 + tc);
    u16x4 hh = {f2bf(v[0]), f2bf(v[1]), f2bf(v[2]), f2bf(v[3])};
    *(u16x4*)&thi[tr][tc] = hh;
    if (out_lo) {
      u16x4 ll = {f2bf(v[0] - bf2f(hh[0])), f2bf(v[1] - bf2f(hh[1])),
                  f2bf(v[2] - bf2f(hh[2])), f2bf(v[3] - bf2f(hh[3]))};
      *(u16x4*)&tlo[tr][tc] = ll;
    }
  }
  __syncthreads();
  #pragma unroll
  for (int a = 0; a < 2; ++a) {
    int idx = t + 256 * a;
    int orow = idx >> 3, oc = (idx & 7) * 8;
    u16x8 vh;
    #pragma unroll
    for (int j = 0; j < 8; ++j) vh[j] = thi[oc + j][orow];
    *(u16x8*)(out_hi + ((size_t)b * outR + c0 + orow) * P + r0 + oc) = vh;
    if (out_lo) {
      u16x8 vl;
      #pragma unroll
      for (int j = 0; j < 8; ++j) vl[j] = tlo[oc + j][orow];
      *(u16x8*)(out_lo + ((size_t)b * outR + c0 + orow) * P + r0 + oc) = vl;
    }
  }
}

// Batched 256x256 weight transposes (z selects).
struct WTab {
  const float* s[8];
  unsigned short* h[8];
  unsigned short* l[8];
};
__global__ __launch_bounds__(256) void wxpose(WTab tab) {
  __shared__ unsigned short thi[64][72], tlo[64][72];
  const int w = blockIdx.z;
  const float* src = tab.s[w];
  unsigned short* oh = tab.h[w];
  unsigned short* ol = tab.l[w];
  const int r0 = blockIdx.x * 64, c0 = blockIdx.y * 64;
  const int t = threadIdx.x;
  #pragma unroll
  for (int a = 0; a < 4; ++a) {
    int idx = t + 256 * a;
    int tr = idx >> 4, tc = (idx & 15) * 4;
    f32x4 v = *(const f32x4*)(src + (size_t)(r0 + tr) * 256 + c0 + tc);
    u16x4 hh = {f2bf(v[0]), f2bf(v[1]), f2bf(v[2]), f2bf(v[3])};
    *(u16x4*)&thi[tr][tc] = hh;
    if (ol) {
      u16x4 ll = {f2bf(v[0] - bf2f(hh[0])), f2bf(v[1] - bf2f(hh[1])),
                  f2bf(v[2] - bf2f(hh[2])), f2bf(v[3] - bf2f(hh[3]))};
      *(u16x4*)&tlo[tr][tc] = ll;
    }
  }
  __syncthreads();
  #pragma unroll
  for (int a = 0; a < 2; ++a) {
    int idx = t + 256 * a;
    int orow = idx >> 3, oc = (idx & 7) * 8;
    u16x8 vh;
    #pragma unroll
    for (int j = 0; j < 8; ++j) vh[j] = thi[oc + j][orow];
    *(u16x8*)(oh + (size_t)(c0 + orow) * 256 + r0 + oc) = vh;
    if (ol) {
      u16x8 vl;
      #pragma unroll
      for (int j = 0; j < 8; ++j) vl[j] = tlo[oc + j][orow];
      *(u16x8*)(ol + (size_t)(c0 + orow) * 256 + r0 + oc) = vl;
    }
  }
}

// ---------------------------------------------------------------------------
// Fused eVT (unscaled bf16) + Y0T (scaled hi/lo) from P1 cols 512..767.
// ---------------------------------------------------------------------------
__global__ __launch_bounds__(256) void xpose_ev(
    const float* __restrict__ P1, unsigned short* __restrict__ eVT,
    unsigned short* __restrict__ yhi, unsigned short* __restrict__ ylo,
    const float* __restrict__ hE) {
  __shared__ unsigned short te[64][72], th[64][72], tl[64][72];
  const int b = blockIdx.z;
  const int r0 = blockIdx.x * 64, c0 = blockIdx.y * 64;
  const int t = threadIdx.x;
  #pragma unroll
  for (int a = 0; a < 4; ++a) {
    int idx = t + 256 * a;
    int tr = idx >> 4, tc = (idx & 15) * 4;
    f32x4 v = *(const f32x4*)(P1 + ((size_t)b * 6144 + r0 + tr) * 768 + 512 + c0 + tc);
    u16x4 eh = {f2bf(v[0]), f2bf(v[1]), f2bf(v[2]), f2bf(v[3])};
    *(u16x4*)&te[tr][tc] = eh;
    float s = hE[((size_t)b * 8 + ((c0 + tc) >> 5)) * 6144 + r0 + tr];
    f32x4 y = v * s;
    u16x4 hh = {f2bf(y[0]), f2bf(y[1]), f2bf(y[2]), f2bf(y[3])};
    *(u16x4*)&th[tr][tc] = hh;
    u16x4 ll = {f2bf(y[0] - bf2f(hh[0])), f2bf(y[1] - bf2f(hh[1])),
                f2bf(y[2] - bf2f(hh[2])), f2bf(y[3] - bf2f(hh[3]))};
    *(u16x4*)&tl[tr][tc] = ll;
  }
  __syncthreads();
  #pragma unroll
  for (int a = 0; a < 2; ++a) {
    int idx = t + 256 * a;
    int orow = idx >> 3, oc = (idx & 7) * 8;
    u16x8 ve, vh, vl;
    #pragma unroll
    for (int j = 0; j < 8; ++j) {
      ve[j] = te[oc + j][orow];
      vh[j] = th[oc + j][orow];
      vl[j] = tl[oc + j][orow];
    }
    size_t o = ((size_t)b * 256 + c0 + orow) * 6144 + r0 + oc;
    *(u16x8*)(eVT + o) = ve;
    *(u16x8*)(yhi + o) = vh;
    *(u16x8*)(ylo + o) = vl;
  }
}

// ---------------------------------------------------------------------------
// rsc_cvt: in fp32 [2][S][R][P] -> out bf16 hi(+lo) [2][R][P], sum S slabs,
// scale by h[b][row>>5][col].
// ---------------------------------------------------------------------------
__global__ void rsc_cvt(const float* __restrict__ in,
                        unsigned short* __restrict__ out_hi,
                        unsigned short* __restrict__ out_lo,
                        const float* __restrict__ h, int S, int R, int P) {
  const long long qP = P >> 2;
  const long long nq = 2LL * R * qP;
  long long i = (long long)blockIdx.x * blockDim.x + threadIdx.x;
  const long long stride = (long long)gridDim.x * blockDim.x;
  for (; i < nq; i += stride) {
    long long b = i / (R * qP);
    long long rem = i - b * (R * qP);
    int row = (int)(rem / qP);
    long long qc = rem - (long long)row * qP;
    const f32x4* base = (const f32x4*)in + ((b * S) * R + row) * qP + qc;
    f32x4 v = base[0];
    for (int s = 1; s < S; ++s) v += base[(long long)s * R * qP];
    v *= *(const f32x4*)(h + ((size_t)b * 8 + (row >> 5)) * P + (qc << 2));
    u16x4 hh = {f2bf(v[0]), f2bf(v[1]), f2bf(v[2]), f2bf(v[3])};
    ((u16x4*)out_hi)[i] = hh;
    if (out_lo) {
      u16x4 ll = {f2bf(v[0] - bf2f(hh[0])), f2bf(v[1] - bf2f(hh[1])),
                  f2bf(v[2] - bf2f(hh[2])), f2bf(v[3] - bf2f(hh[3]))};
      ((u16x4*)out_lo)[i] = ll;
    }
  }
}

// ---------------------------------------------------------------------------
// v-pair hval, numpy-fp32-exact (validated R3). 8 rows per block.
// ---------------------------------------------------------------------------
__global__ __launch_bounds__(256) void vproj_hval_np(
    const float* __restrict__ X, const float* __restrict__ Wq,
    const float* __restrict__ Wk, float* __restrict__ hout, int P) {
  __shared__ float sx[8][256], sq[8][256], sk[8][256];
  const int r0 = blockIdx.x * 8;
  const int j = threadIdx.x;
  #pragma unroll
  for (int r = 0; r < 8; ++r) sx[r][j] = X[(size_t)(r0 + r) * 256 + j];
  __syncthreads();
  float qa[8] = {}, ka[8] = {};
  for (int i = 0; i < 256; ++i) {
    float wq = Wq[i * 256 + j], wk = Wk[i * 256 + j];
    #pragma unroll
    for (int r = 0; r < 8; ++r) {
      qa[r] = __fmaf_rn(sx[r][i], wq, qa[r]);
      ka[r] = __fmaf_rn(sx[r][i], wk, ka[r]);
    }
  }
  #pragma unroll
  for (int r = 0; r < 8; ++r) { sq[r][j] = qa[r]; sk[r][j] = ka[r]; }
  __syncthreads();
  if (j < 64) {
    const int r = j >> 3, head = j & 7;
    const float* qq = &sq[r][head * 32];
    const float* kk = &sk[r][head * 32];
    float s0 = 0.0f, s1 = 0.0f, s2 = 0.0f, s3 = 0.0f;
    #pragma unroll 1
    for (int d = 0; d < 32; d += 4) {
      s0 = __fadd_rn(s0, __fmul_rn(qq[d + 0], kk[d + 0]));
      s1 = __fadd_rn(s1, __fmul_rn(qq[d + 1], kk[d + 1]));
      s2 = __fadd_rn(s2, __fmul_rn(qq[d + 2], kk[d + 2]));
      s3 = __fadd_rn(s3, __fmul_rn(qq[d + 3], kk[d + 3]));
    }
    float p = __fadd_rn(__fadd_rn(s0, s2), __fadd_rn(s1, s3));
    float hval = __fdiv_rn(p, sqrtf(32.0f));
    float inv = __fdiv_rn(1.0f, __fadd_rn(hval, 1e-6f));
    const int row = r0 + r;
    const int b = row / P, pos = row - b * P;
    hout[((size_t)b * 8 + head) * P + pos] = inv;
  }
}

// hval = rowwise per-head dot of fp32 Q,K (ld = row stride). One wave/row.
__global__ __launch_bounds__(256) void dot_hval(
    const float* __restrict__ Q, const float* __restrict__ K,
    float* __restrict__ hout, int P, int ld) {
  const int wv = threadIdx.x >> 6, lane = threadIdx.x & 63;
  const int row = blockIdx.x * 4 + wv;
  f32x4 q = *(const f32x4*)(Q + (size_t)row * ld + lane * 4);
  f32x4 k = *(const f32x4*)(K + (size_t)row * ld + lane * 4);
  float p = q[0] * k[0] + q[1] * k[1] + q[2] * k[2] + q[3] * k[3];
  p += __shfl_xor(p, 1);
  p += __shfl_xor(p, 2);
  p += __shfl_xor(p, 4);
  if ((lane & 7) == 0) {
    const int head = lane >> 3;
    const int b = row / P, pos = row % P;
    hout[((size_t)b * 8 + head) * P + pos] = p * 0.17677669529663687f;
  }
}

// ---------------------------------------------------------------------------
extern "C" void kernel_launch(void* const* d_in, const int* in_sizes, int n_in,
                              void* d_out, int out_size, void* d_ws, size_t ws_size,
                              hipStream_t stream) {
  const float* x_v = (const float*)d_in[0];
  const float* x_e = (const float*)d_in[1];
  const float* x_f = (const float*)d_in[2];
  const float* d0  = (const float*)d_in[3];   // (2, 6144, 2048)
  const float* d1  = (const float*)d_in[4];   // (2, 4096, 6144)
  const float* W_vq = (const float*)d_in[5];
  const float* W_vk = (const float*)d_in[6];
  float* out = (float*)d_out;

  const int NV = 2048, ME = 6144, KF = 4096;
  const float* NF = nullptr;
  const unsigned short* NUS = nullptr;

  char* ws = (char*)d_ws;
  size_t o = 0;
  auto alloc = [&](size_t bytes) { size_t r = o; o = (o + bytes + 255) & ~255ULL; return r; };

  unsigned short* WcatE_hi = (unsigned short*)(ws + alloc(768 * 256 * 2));
  unsigned short* WcatE_lo = (unsigned short*)(ws + alloc(768 * 256 * 2));
  unsigned short* W2_hi = (unsigned short*)(ws + alloc(512 * 256 * 2));
  unsigned short* W3_hi = (unsigned short*)(ws + alloc(512 * 256 * 2));
  unsigned short* Wo_hi = (unsigned short*)(ws + alloc(256 * 256 * 2));
  unsigned short* Wo_lo = (unsigned short*)(ws + alloc(256 * 256 * 2));
  float* pHvE  = (float*)(ws + alloc(2 * 8 * ME * 4));
  float* pHvEi = (float*)(ws + alloc(2 * 8 * ME * 4));
  float* pHvF  = (float*)(ws + alloc(2 * 8 * KF * 4));
  float* pHvV  = (float*)(ws + alloc(2 * 8 * NV * 4));
  unsigned short* d1T_hi = (unsigned short*)(ws + alloc((size_t)2 * ME * KF * 2));   // [2][6144][4096]
  unsigned short* d0T_hi = (unsigned short*)(ws + alloc((size_t)2 * NV * ME * 2));   // [2][2048][6144]
  unsigned short* d0T_lo = (unsigned short*)(ws + alloc((size_t)2 * NV * ME * 2));
  unsigned short* eVT_hi = (unsigned short*)(ws + alloc((size_t)2 * 256 * ME * 2));  // [2][256][6144]
  unsigned short* Y0T_hi = (unsigned short*)(ws + alloc((size_t)2 * 256 * ME * 2));
  unsigned short* Y0T_lo = (unsigned short*)(ws + alloc((size_t)2 * 256 * ME * 2));
  unsigned short* T1sT_hi = (unsigned short*)(ws + alloc((size_t)2 * 256 * KF * 2)); // [2][256][4096]
  unsigned short* T3sT_hi = (unsigned short*)(ws + alloc((size_t)2 * 256 * NV * 2)); // [2][256][2048]
  unsigned short* T3sT_lo = (unsigned short*)(ws + alloc((size_t)2 * 256 * NV * 2));
  float* pP1 = (float*)(ws + alloc((size_t)12288 * 768 * 4));       // projections e
  float* pP2 = (float*)(ws + alloc((size_t)12288 * 512 * 4));
  float* pP3 = (float*)(ws + alloc((size_t)8192 * 512 * 4));
  float* pTp = (float*)(ws + alloc((size_t)2 * 12 * 256 * 2048 * 4));  // T1^T / T3^T slabs
  float* pT2p = (float*)(ws + alloc((size_t)2 * 4 * ME * 256 * 4));
  float* pT4p = (float*)(ws + alloc((size_t)2 * 4 * ME * 256 * 4));

  dim3 blk(256);

  // --- batched weight transposes -> bf16 [n][k] ---
  WTab tab;
  tab.s[0] = (const float*)d_in[7];  tab.h[0] = WcatE_hi;           tab.l[0] = WcatE_lo;            // eq
  tab.s[1] = (const float*)d_in[8];  tab.h[1] = WcatE_hi + 65536;   tab.l[1] = WcatE_lo + 65536;    // ek
  tab.s[2] = (const float*)d_in[11]; tab.h[2] = WcatE_hi + 131072;  tab.l[2] = WcatE_lo + 131072;   // ev
  tab.s[3] = (const float*)d_in[9];  tab.h[3] = W2_hi;              tab.l[3] = nullptr;             // einvq
  tab.s[4] = (const float*)d_in[10]; tab.h[4] = W2_hi + 65536;      tab.l[4] = nullptr;             // einvk
  tab.s[5] = (const float*)d_in[12]; tab.h[5] = W3_hi;              tab.l[5] = nullptr;             // fq
  tab.s[6] = (const float*)d_in[13]; tab.h[6] = W3_hi + 65536;      tab.l[6] = nullptr;             // fk
  tab.s[7] = (const float*)d_in[14]; tab.h[7] = Wo_hi;              tab.l[7] = Wo_lo;               // o
  wxpose<<<dim3(4, 4, 8), blk, 0, stream>>>(tab);

  // --- d-matrix transposes (once) ---
  xpose_cvt<<<dim3(64, 96, 2), blk, 0, stream>>>(d1, d1T_hi, nullptr, (long long)KF * ME, KF, ME, ME);
  xpose_cvt<<<dim3(96, 32, 2), blk, 0, stream>>>(d0, d0T_hi, d0T_lo, (long long)ME * NV, ME, NV, NV);

  // --- v hval (np-fp32 exact) ---
  vproj_hval_np<<<512, blk, 0, stream>>>(x_v, W_vq, W_vk, pHvV, NV);

  // --- projections ---
  gemm_ws<false, false, true, false><<<dim3(96, 6, 1), blk, 0, stream>>>(
      x_e, NUS, NUS, NF, WcatE_hi, WcatE_lo, pP1, 256, 256, 256, 1, 0, 0, 0);
  dot_hval<<<3072, blk, 0, stream>>>(pP1, pP1 + 256, pHvE, ME, 768);
  xpose_ev<<<dim3(96, 4, 2), blk, 0, stream>>>(pP1, eVT_hi, Y0T_hi, Y0T_lo, pHvE);
  gemm_ws<false, false, false, false><<<dim3(96, 4, 1), blk, 0, stream>>>(
      x_e, NUS, NUS, NF, W2_hi, NUS, pP2, 256, 256, 256, 1, 0, 0, 0);
  dot_hval<<<3072, blk, 0, stream>>>(pP2, pP2 + 256, pHvEi, ME, 512);
  gemm_ws<false, false, false, false><<<dim3(64, 4, 1), blk, 0, stream>>>(
      x_f, NUS, NUS, NF, W3_hi, NUS, pP3, 256, 256, 256, 1, 0, 0, 0);
  dot_hval<<<2048, blk, 0, stream>>>(pP3, pP3 + 256, pHvF, KF, 512);

  // --- up branch ---
  // T1^T = eVT @ d1 (B natural fp32, cvt in staging), S=6 -> [2][6][256][4096]
  gemm_ws<true, true, false, true><<<dim3(2, 32, 12), blk, 0, stream>>>(
      NF, eVT_hi, NUS, d1, NUS, NUS, pTp, ME, ME, ME, 6,
      256LL * ME, (long long)KF * ME, 256LL * KF);
  // T1sT = sum slabs * f_hval -> bf16 [2][256][4096]
  rsc_cvt<<<2048, blk, 0, stream>>>(pTp, T1sT_hi, nullptr, pHvF, 6, 256, KF);
  // T2 = d1T @ T1s, S=4 -> [2][4][6144][256]
  gemm_ws<true, false, false, false><<<dim3(48, 2, 8), blk, 0, stream>>>(
      NF, d1T_hi, NUS, NF, T1sT_hi, NUS, pT2p, KF, KF, KF, 4,
      (long long)ME * KF, 256LL * KF, (long long)ME * 256);

  // --- down branch ---
  // T3^T = Y0T @ d0T-as-B (split), S=12 -> [2][12][256][2048]
  gemm_ws<true, false, true, true><<<dim3(2, 16, 24), blk, 0, stream>>>(
      NF, Y0T_hi, Y0T_lo, NF, d0T_hi, d0T_lo, pTp, ME, ME, ME, 12,
      256LL * ME, (long long)NV * ME, 256LL * NV);
  // T3sT = sum slabs * v_inv -> bf16 hi/lo [2][256][2048]
  rsc_cvt<<<1024, blk, 0, stream>>>(pTp, T3sT_hi, T3sT_lo, pHvV, 12, 256, NV);
  // T4 = d0 @ T3s (split), S=4 -> [2][4][6144][256]
  gemm_ws<false, false, true, false><<<dim3(48, 2, 8), blk, 0, stream>>>(
      d0, NUS, NUS, NF, T3sT_hi, T3sT_lo, pT4p, NV, NV, NV, 4,
      (long long)ME * NV, 256LL * NV, (long long)ME * 256);

  // --- fused combine + output projection ---
  gemm_out<<<dim3(96, 2, 1), blk, 0, stream>>>(pT2p, pT4p, pHvEi, Wo_hi, Wo_lo, out);
}

// Round 7
// 536.557 us; speedup vs baseline: 2.4497x; 1.1098x over previous
//
#include <hip/hip_runtime.h>
#include <hip/hip_bf16.h>
#include <cstdint>
#include <cstddef>

// ---------------------------------------------------------------------------
// MeshMultiHeadHodgeLaplaceAttention  (b=2, n=2048, m=6144, k=4096, D=256, H=8)
//
//   up:   T1 = d_1 @ eV ; *f_hval ; T2 = d_1^T @ T1s ; (*einv_hval in combine)
//   down: Y0 = eV*e_hval ; T3 = d_0^T @ Y0 ; *1/(v_hval+eps) ; T4 = d_0 @ T3s
//   out = (T2*einv_hval + T4) @ W_o
//
// Precision (validated R3-R6): v_hval replicates numpy fp32 bit-exactly;
// amplified chain {e/einv/ev proj, T3, T4, out} split-bf16 (hi/lo, 3 MFMA);
// up branch plain bf16.
//
// R7: natural-layout bf16 d0/d1 copies (vector staging, half HBM bytes);
// register-prefetch K-loop (loads hidden under MFMA); T1||T3 and T2||T4
// tail overlap; merged N=1280 projection GEMM + fused double hval dot.
// ---------------------------------------------------------------------------

typedef __attribute__((ext_vector_type(4))) float f32x4;
typedef __attribute__((ext_vector_type(4))) unsigned short u16x4;
typedef __attribute__((ext_vector_type(8))) unsigned short u16x8;
typedef __attribute__((ext_vector_type(8))) __bf16 bf16x8;

static __device__ __forceinline__ unsigned short f2bf(float f) {
  uint32_t u = __builtin_bit_cast(uint32_t, f);
  uint32_t r = (u + 0x7FFFu + ((u >> 16) & 1u)) >> 16;  // RNE
  return (unsigned short)r;
}
static __device__ __forceinline__ float bf2f(unsigned short h) {
  return __builtin_bit_cast(float, (uint32_t)h << 16);
}

// ---------------------------------------------------------------------------
// GEMM: C[M x NC] = A[M x K] * B[N x K]^T-layout, NC = gridDim.y*128.
// A: fp32 [M][K] cvt-in-staging (!ABF) or bf16 hi(/lo) [M][K] (ABF).
// B: bf16 hi(/lo) [N][K].
// Split-K: blockIdx.z = batch*S + split; each split writes its own C slab.
// Register-prefetch: next tile's global loads issued under current MFMA.
// 128x128 tile, BK=32, 4 waves 2x2, each 4x4 16x16x32 frags.
// ---------------------------------------------------------------------------
template <bool ABF, bool SPLIT, bool XFAST>
__global__ __launch_bounds__(256) void gemm_ws(
    const float* __restrict__ Af, const unsigned short* __restrict__ Ah,
    const unsigned short* __restrict__ Al,
    const unsigned short* __restrict__ Bh, const unsigned short* __restrict__ Bl,
    float* __restrict__ C, int K, int ldA, int ldB, int S,
    long long sA, long long sB, long long sC) {
  const int z = blockIdx.z;
  const int batch = z / S, split = z - batch * S;
  if constexpr (ABF) {
    Ah += (long long)batch * sA;
    if constexpr (SPLIT) Al += (long long)batch * sA;
  } else {
    Af += (long long)batch * sA;
  }
  Bh += (long long)batch * sB;
  if constexpr (SPLIT) Bl += (long long)batch * sB;
  C += (long long)z * sC;

  // XCD-bijective swizzle
  const int gx = gridDim.x, gy = gridDim.y;
  const int nwg = gx * gy;
  const int wid = blockIdx.x + gx * blockIdx.y;
  const int q = nwg >> 3, r = nwg & 7;
  const int xcd = wid & 7, posn = wid >> 3;
  const int swz = (xcd < r ? xcd * (q + 1) : r * (q + 1) + (xcd - r) * q) + posn;
  int mt, nt;
  if constexpr (XFAST) { mt = swz % gx; nt = swz / gx; }
  else                 { mt = swz / gy; nt = swz - mt * gy; }
  const int m0 = mt * 128, n0 = nt * 128;
  const int NC = gy << 7;

  const int kLen = K / S, k0base = split * kLen;
  constexpr int NBUF = SPLIT ? 4 : 2;
  __shared__ unsigned short lds[NBUF][128][40];  // [0]=Ah [1]=Bh [2]=Al [3]=Bl

  const int t = threadIdx.x;
  const int wid4 = t >> 6, lane = t & 63;
  const int wr = wid4 >> 1, wc = wid4 & 1;
  const int lr = lane & 15, kq = lane >> 4;

  // staging decompositions
  const int rowA8 = t >> 3, qdA = (t & 7) * 4;       // fp32 A: +32 rows per iter
  const int rowV = t >> 2, c8V = (t & 3) * 8;        // bf16 u16x8: +64 rows per iter

  f32x4 rAf[4];
  u16x8 rAh[2], rAl[2], rBh[2], rBl[2];

  auto LOAD = [&](int kb) {
    if constexpr (!ABF) {
      #pragma unroll
      for (int a = 0; a < 4; ++a)
        rAf[a] = *(const f32x4*)(Af + (size_t)(m0 + rowA8 + 32 * a) * ldA + kb + qdA);
    } else {
      #pragma unroll
      for (int a = 0; a < 2; ++a) {
        rAh[a] = *(const u16x8*)(Ah + (size_t)(m0 + rowV + 64 * a) * ldA + kb + c8V);
        if constexpr (SPLIT)
          rAl[a] = *(const u16x8*)(Al + (size_t)(m0 + rowV + 64 * a) * ldA + kb + c8V);
      }
    }
    #pragma unroll
    for (int a = 0; a < 2; ++a) {
      rBh[a] = *(const u16x8*)(Bh + (size_t)(n0 + rowV + 64 * a) * ldB + kb + c8V);
      if constexpr (SPLIT)
        rBl[a] = *(const u16x8*)(Bl + (size_t)(n0 + rowV + 64 * a) * ldB + kb + c8V);
    }
  };
  auto STORE = [&]() {
    if constexpr (!ABF) {
      #pragma unroll
      for (int a = 0; a < 4; ++a) {
        f32x4 v = rAf[a];
        u16x4 h = {f2bf(v[0]), f2bf(v[1]), f2bf(v[2]), f2bf(v[3])};
        *(u16x4*)&lds[0][rowA8 + 32 * a][qdA] = h;
        if constexpr (SPLIT) {
          u16x4 l = {f2bf(v[0] - bf2f(h[0])), f2bf(v[1] - bf2f(h[1])),
                     f2bf(v[2] - bf2f(h[2])), f2bf(v[3] - bf2f(h[3]))};
          *(u16x4*)&lds[2][rowA8 + 32 * a][qdA] = l;
        }
      }
    } else {
      #pragma unroll
      for (int a = 0; a < 2; ++a) {
        *(u16x8*)&lds[0][rowV + 64 * a][c8V] = rAh[a];
        if constexpr (SPLIT) *(u16x8*)&lds[2][rowV + 64 * a][c8V] = rAl[a];
      }
    }
    #pragma unroll
    for (int a = 0; a < 2; ++a) {
      *(u16x8*)&lds[1][rowV + 64 * a][c8V] = rBh[a];
      if constexpr (SPLIT) *(u16x8*)&lds[3][rowV + 64 * a][c8V] = rBl[a];
    }
  };

  f32x4 acc[4][4] = {};

  LOAD(k0base);
  for (int kk = 0; kk < kLen; kk += 32) {
    STORE();
    __syncthreads();
    if (kk + 32 < kLen) LOAD(k0base + kk + 32);  // prefetch under MFMA

    bf16x8 ah[4], bh[4], al[4], bl[4];
    #pragma unroll
    for (int i = 0; i < 4; ++i) {
      ah[i] = __builtin_bit_cast(bf16x8, *(const u16x8*)&lds[0][wr * 64 + i * 16 + lr][kq * 8]);
      bh[i] = __builtin_bit_cast(bf16x8, *(const u16x8*)&lds[1][wc * 64 + i * 16 + lr][kq * 8]);
      if constexpr (SPLIT) {
        al[i] = __builtin_bit_cast(bf16x8, *(const u16x8*)&lds[2][wr * 64 + i * 16 + lr][kq * 8]);
        bl[i] = __builtin_bit_cast(bf16x8, *(const u16x8*)&lds[3][wc * 64 + i * 16 + lr][kq * 8]);
      }
    }
    #pragma unroll
    for (int i = 0; i < 4; ++i)
      #pragma unroll
      for (int j = 0; j < 4; ++j) {
        acc[i][j] = __builtin_amdgcn_mfma_f32_16x16x32_bf16(ah[i], bh[j], acc[i][j], 0, 0, 0);
        if constexpr (SPLIT) {
          acc[i][j] = __builtin_amdgcn_mfma_f32_16x16x32_bf16(ah[i], bl[j], acc[i][j], 0, 0, 0);
          acc[i][j] = __builtin_amdgcn_mfma_f32_16x16x32_bf16(al[i], bh[j], acc[i][j], 0, 0, 0);
        }
      }
    __syncthreads();
  }

  // epilogue: D mapping col = lane&15, row = (lane>>4)*4 + q
  #pragma unroll
  for (int i = 0; i < 4; ++i)
    #pragma unroll
    for (int j = 0; j < 4; ++j) {
      float* cp = C + (size_t)(m0 + wr * 64 + i * 16 + kq * 4) * NC + n0 + wc * 64 + j * 16 + lr;
      #pragma unroll
      for (int qq = 0; qq < 4; ++qq) cp[(size_t)qq * NC] = acc[i][j][qq];
    }
}

// ---------------------------------------------------------------------------
// Output GEMM with fused combine: A[r][c] = (T4p 4-slab sum) +
// (T2p 4-slab sum)*einv_hval;  C = A @ W_o (split hi/lo). M=12288,N=256,K=256.
// ---------------------------------------------------------------------------
__global__ __launch_bounds__(256) void gemm_out(
    const float* __restrict__ T2p, const float* __restrict__ T4p,
    const float* __restrict__ hEi, const unsigned short* __restrict__ Bh,
    const unsigned short* __restrict__ Bl, float* __restrict__ C) {
  const int gx = gridDim.x, gy = gridDim.y;
  const int nwg = gx * gy;
  const int wid = blockIdx.x + gx * blockIdx.y;
  const int q = nwg >> 3, r = nwg & 7;
  const int xcd = wid & 7, posn = wid >> 3;
  const int swz = (xcd < r ? xcd * (q + 1) : r * (q + 1) + (xcd - r) * q) + posn;
  const int mt = swz / gy;
  const int m0 = mt * 128, n0 = (swz - mt * gy) * 128;

  __shared__ unsigned short lds[4][128][40];
  const int t = threadIdx.x;
  const int wid4 = t >> 6, lane = t & 63;
  const int wr = wid4 >> 1, wc = wid4 & 1;
  const int lr = lane & 15, kq = lane >> 4;
  const long long slab = 6144LL * 256;

  f32x4 acc[4][4] = {};

  for (int kb = 0; kb < 256; kb += 32) {
    #pragma unroll
    for (int a = 0; a < 4; ++a) {
      int idx = t + 256 * a;
      int row = idx >> 3, qd = (idx & 7) * 4;
      int rg = m0 + row;
      int b = rg >= 6144;
      int pos = rg - b * 6144;
      int ck = kb + qd;
      float s = hEi[((size_t)b * 8 + (ck >> 5)) * 6144 + pos];
      const float* b2 = T2p + ((long long)(b * 4) * 6144 + pos) * 256 + ck;
      const float* b4 = T4p + ((long long)(b * 4) * 6144 + pos) * 256 + ck;
      f32x4 t2 = (*(const f32x4*)b2 + *(const f32x4*)(b2 + slab)) +
                 (*(const f32x4*)(b2 + 2 * slab) + *(const f32x4*)(b2 + 3 * slab));
      f32x4 t4 = (*(const f32x4*)b4 + *(const f32x4*)(b4 + slab)) +
                 (*(const f32x4*)(b4 + 2 * slab) + *(const f32x4*)(b4 + 3 * slab));
      f32x4 v = t4 + t2 * s;
      u16x4 h = {f2bf(v[0]), f2bf(v[1]), f2bf(v[2]), f2bf(v[3])};
      *(u16x4*)&lds[0][row][qd] = h;
      u16x4 l = {f2bf(v[0] - bf2f(h[0])), f2bf(v[1] - bf2f(h[1])),
                 f2bf(v[2] - bf2f(h[2])), f2bf(v[3] - bf2f(h[3]))};
      *(u16x4*)&lds[2][row][qd] = l;
    }
    #pragma unroll
    for (int a = 0; a < 2; ++a) {
      int idx = t + 256 * a;
      int row = idx >> 2, c8 = (idx & 3) * 8;
      *(u16x8*)&lds[1][row][c8] = *(const u16x8*)(Bh + (size_t)(n0 + row) * 256 + kb + c8);
      *(u16x8*)&lds[3][row][c8] = *(const u16x8*)(Bl + (size_t)(n0 + row) * 256 + kb + c8);
    }
    __syncthreads();

    bf16x8 ah[4], bh[4], al[4], bl[4];
    #pragma unroll
    for (int i = 0; i < 4; ++i) {
      ah[i] = __builtin_bit_cast(bf16x8, *(const u16x8*)&lds[0][wr * 64 + i * 16 + lr][kq * 8]);
      bh[i] = __builtin_bit_cast(bf16x8, *(const u16x8*)&lds[1][wc * 64 + i * 16 + lr][kq * 8]);
      al[i] = __builtin_bit_cast(bf16x8, *(const u16x8*)&lds[2][wr * 64 + i * 16 + lr][kq * 8]);
      bl[i] = __builtin_bit_cast(bf16x8, *(const u16x8*)&lds[3][wc * 64 + i * 16 + lr][kq * 8]);
    }
    #pragma unroll
    for (int i = 0; i < 4; ++i)
      #pragma unroll
      for (int j = 0; j < 4; ++j) {
        acc[i][j] = __builtin_amdgcn_mfma_f32_16x16x32_bf16(ah[i], bh[j], acc[i][j], 0, 0, 0);
        acc[i][j] = __builtin_amdgcn_mfma_f32_16x16x32_bf16(ah[i], bl[j], acc[i][j], 0, 0, 0);
        acc[i][j] = __builtin_amdgcn_mfma_f32_16x16x32_bf16(al[i], bh[j], acc[i][j], 0, 0, 0);
      }
    __syncthreads();
  }

  #pragma unroll
  for (int i = 0; i < 4; ++i)
    #pragma unroll
    for (int j = 0; j < 4; ++j) {
      float* cp = C + (size_t)(m0 + wr * 64 + i * 16 + kq * 4) * 256 + n0 + wc * 64 + j * 16 + lr;
      #pragma unroll
      for (int qq = 0; qq < 4; ++qq) cp[(size_t)qq * 256] = acc[i][j][qq];
    }
}

// ---------------------------------------------------------------------------
// d1 pass: reads d1 [2][4096][6144] fp32; writes d1N_hi (natural bf16) and
// d1T_hi (transposed bf16 [2][6144][4096]).
// ---------------------------------------------------------------------------
__global__ __launch_bounds__(256) void xpose_d1(
    const float* __restrict__ d1, unsigned short* __restrict__ d1T,
    unsigned short* __restrict__ d1N) {
  __shared__ unsigned short thi[64][72];
  const int b = blockIdx.z;
  const int r0 = blockIdx.x * 64, c0 = blockIdx.y * 64;  // r=face, c=edge
  const int t = threadIdx.x;
  #pragma unroll
  for (int a = 0; a < 4; ++a) {
    int idx = t + 256 * a;
    int tr = idx >> 4, tc = (idx & 15) * 4;
    f32x4 v = *(const f32x4*)(d1 + ((size_t)b * 4096 + r0 + tr) * 6144 + c0 + tc);
    u16x4 hh = {f2bf(v[0]), f2bf(v[1]), f2bf(v[2]), f2bf(v[3])};
    *(u16x4*)&thi[tr][tc] = hh;
    *(u16x4*)(d1N + ((size_t)b * 4096 + r0 + tr) * 6144 + c0 + tc) = hh;
  }
  __syncthreads();
  #pragma unroll
  for (int a = 0; a < 2; ++a) {
    int idx = t + 256 * a;
    int orow = idx >> 3, oc = (idx & 7) * 8;
    u16x8 vh;
    #pragma unroll
    for (int j = 0; j < 8; ++j) vh[j] = thi[oc + j][orow];
    *(u16x8*)(d1T + ((size_t)b * 6144 + c0 + orow) * 4096 + r0 + oc) = vh;
  }
}

// ---------------------------------------------------------------------------
// d0 pass: reads d0 [2][6144][2048] fp32; writes d0N hi/lo (natural) and
// d0T hi/lo (transposed [2][2048][6144]).
// ---------------------------------------------------------------------------
__global__ __launch_bounds__(256) void xpose_d0(
    const float* __restrict__ d0, unsigned short* __restrict__ d0T_hi,
    unsigned short* __restrict__ d0T_lo, unsigned short* __restrict__ d0N_hi,
    unsigned short* __restrict__ d0N_lo) {
  __shared__ unsigned short thi[64][72], tlo[64][72];
  const int b = blockIdx.z;
  const int r0 = blockIdx.x * 64, c0 = blockIdx.y * 64;  // r=edge, c=vertex
  const int t = threadIdx.x;
  #pragma unroll
  for (int a = 0; a < 4; ++a) {
    int idx = t + 256 * a;
    int tr = idx >> 4, tc = (idx & 15) * 4;
    size_t off = ((size_t)b * 6144 + r0 + tr) * 2048 + c0 + tc;
    f32x4 v = *(const f32x4*)(d0 + off);
    u16x4 hh = {f2bf(v[0]), f2bf(v[1]), f2bf(v[2]), f2bf(v[3])};
    u16x4 ll = {f2bf(v[0] - bf2f(hh[0])), f2bf(v[1] - bf2f(hh[1])),
                f2bf(v[2] - bf2f(hh[2])), f2bf(v[3] - bf2f(hh[3]))};
    *(u16x4*)&thi[tr][tc] = hh;
    *(u16x4*)&tlo[tr][tc] = ll;
    *(u16x4*)(d0N_hi + off) = hh;
    *(u16x4*)(d0N_lo + off) = ll;
  }
  __syncthreads();
  #pragma unroll
  for (int a = 0; a < 2; ++a) {
    int idx = t + 256 * a;
    int orow = idx >> 3, oc = (idx & 7) * 8;
    u16x8 vh, vl;
    #pragma unroll
    for (int j = 0; j < 8; ++j) { vh[j] = thi[oc + j][orow]; vl[j] = tlo[oc + j][orow]; }
    size_t o = ((size_t)b * 2048 + c0 + orow) * 6144 + r0 + oc;
    *(u16x8*)(d0T_hi + o) = vh;
    *(u16x8*)(d0T_lo + o) = vl;
  }
}

// Batched 256x256 weight transposes (z selects).
struct WTab {
  const float* s[8];
  unsigned short* h[8];
  unsigned short* l[8];
};
__global__ __launch_bounds__(256) void wxpose(WTab tab) {
  __shared__ unsigned short thi[64][72], tlo[64][72];
  const int w = blockIdx.z;
  const float* src = tab.s[w];
  unsigned short* oh = tab.h[w];
  unsigned short* ol = tab.l[w];
  const int r0 = blockIdx.x * 64, c0 = blockIdx.y * 64;
  const int t = threadIdx.x;
  #pragma unroll
  for (int a = 0; a < 4; ++a) {
    int idx = t + 256 * a;
    int tr = idx >> 4, tc = (idx & 15) * 4;
    f32x4 v = *(const f32x4*)(src + (size_t)(r0 + tr) * 256 + c0 + tc);
    u16x4 hh = {f2bf(v[0]), f2bf(v[1]), f2bf(v[2]), f2bf(v[3])};
    *(u16x4*)&thi[tr][tc] = hh;
    if (ol) {
      u16x4 ll = {f2bf(v[0] - bf2f(hh[0])), f2bf(v[1] - bf2f(hh[1])),
                  f2bf(v[2] - bf2f(hh[2])), f2bf(v[3] - bf2f(hh[3]))};
      *(u16x4*)&tlo[tr][tc] = ll;
    }
  }
  __syncthreads();
  #pragma unroll
  for (int a = 0; a < 2; ++a) {
    int idx = t + 256 * a;
    int orow = idx >> 3, oc = (idx & 7) * 8;
    u16x8 vh;
    #pragma unroll
    for (int j = 0; j < 8; ++j) vh[j] = thi[oc + j][orow];
    *(u16x8*)(oh + (size_t)(c0 + orow) * 256 + r0 + oc) = vh;
    if (ol) {
      u16x8 vl;
      #pragma unroll
      for (int j = 0; j < 8; ++j) vl[j] = tlo[oc + j][orow];
      *(u16x8*)(ol + (size_t)(c0 + orow) * 256 + r0 + oc) = vl;
    }
  }
}

// ---------------------------------------------------------------------------
// Fused eVT (unscaled bf16) + Y0T (scaled hi/lo) from P1 cols 512..767
// (row stride 1280).
// ---------------------------------------------------------------------------
__global__ __launch_bounds__(256) void xpose_ev(
    const float* __restrict__ P1, unsigned short* __restrict__ eVT,
    unsigned short* __restrict__ yhi, unsigned short* __restrict__ ylo,
    const float* __restrict__ hE) {
  __shared__ unsigned short te[64][72], th[64][72], tl[64][72];
  const int b = blockIdx.z;
  const int r0 = blockIdx.x * 64, c0 = blockIdx.y * 64;
  const int t = threadIdx.x;
  #pragma unroll
  for (int a = 0; a < 4; ++a) {
    int idx = t + 256 * a;
    int tr = idx >> 4, tc = (idx & 15) * 4;
    f32x4 v = *(const f32x4*)(P1 + ((size_t)b * 6144 + r0 + tr) * 1280 + 512 + c0 + tc);
    u16x4 eh = {f2bf(v[0]), f2bf(v[1]), f2bf(v[2]), f2bf(v[3])};
    *(u16x4*)&te[tr][tc] = eh;
    float s = hE[((size_t)b * 8 + ((c0 + tc) >> 5)) * 6144 + r0 + tr];
    f32x4 y = v * s;
    u16x4 hh = {f2bf(y[0]), f2bf(y[1]), f2bf(y[2]), f2bf(y[3])};
    *(u16x4*)&th[tr][tc] = hh;
    u16x4 ll = {f2bf(y[0] - bf2f(hh[0])), f2bf(y[1] - bf2f(hh[1])),
                f2bf(y[2] - bf2f(hh[2])), f2bf(y[3] - bf2f(hh[3]))};
    *(u16x4*)&tl[tr][tc] = ll;
  }
  __syncthreads();
  #pragma unroll
  for (int a = 0; a < 2; ++a) {
    int idx = t + 256 * a;
    int orow = idx >> 3, oc = (idx & 7) * 8;
    u16x8 ve, vh, vl;
    #pragma unroll
    for (int j = 0; j < 8; ++j) {
      ve[j] = te[oc + j][orow];
      vh[j] = th[oc + j][orow];
      vl[j] = tl[oc + j][orow];
    }
    size_t o = ((size_t)b * 256 + c0 + orow) * 6144 + r0 + oc;
    *(u16x8*)(eVT + o) = ve;
    *(u16x8*)(yhi + o) = vh;
    *(u16x8*)(ylo + o) = vl;
  }
}

// ---------------------------------------------------------------------------
// rsc_cvt: in fp32 [2][S][R][P] -> out bf16 hi(+lo) [2][R][P], sum S slabs,
// scale by h[b][row>>5][col].
// ---------------------------------------------------------------------------
__global__ void rsc_cvt(const float* __restrict__ in,
                        unsigned short* __restrict__ out_hi,
                        unsigned short* __restrict__ out_lo,
                        const float* __restrict__ h, int S, int R, int P) {
  const long long qP = P >> 2;
  const long long nq = 2LL * R * qP;
  long long i = (long long)blockIdx.x * blockDim.x + threadIdx.x;
  const long long stride = (long long)gridDim.x * blockDim.x;
  for (; i < nq; i += stride) {
    long long b = i / (R * qP);
    long long rem = i - b * (R * qP);
    int row = (int)(rem / qP);
    long long qc = rem - (long long)row * qP;
    const f32x4* base = (const f32x4*)in + ((b * S) * R + row) * qP + qc;
    f32x4 v = base[0];
    for (int s = 1; s < S; ++s) v += base[(long long)s * R * qP];
    v *= *(const f32x4*)(h + ((size_t)b * 8 + (row >> 5)) * P + (qc << 2));
    u16x4 hh = {f2bf(v[0]), f2bf(v[1]), f2bf(v[2]), f2bf(v[3])};
    ((u16x4*)out_hi)[i] = hh;
    if (out_lo) {
      u16x4 ll = {f2bf(v[0] - bf2f(hh[0])), f2bf(v[1] - bf2f(hh[1])),
                  f2bf(v[2] - bf2f(hh[2])), f2bf(v[3] - bf2f(hh[3]))};
      ((u16x4*)out_lo)[i] = ll;
    }
  }
}

// ---------------------------------------------------------------------------
// v-pair hval, numpy-fp32-exact (validated R3). 8 rows per block.
// ---------------------------------------------------------------------------
__global__ __launch_bounds__(256) void vproj_hval_np(
    const float* __restrict__ X, const float* __restrict__ Wq,
    const float* __restrict__ Wk, float* __restrict__ hout, int P) {
  __shared__ float sx[8][256], sq[8][256], sk[8][256];
  const int r0 = blockIdx.x * 8;
  const int j = threadIdx.x;
  #pragma unroll
  for (int r = 0; r < 8; ++r) sx[r][j] = X[(size_t)(r0 + r) * 256 + j];
  __syncthreads();
  float qa[8] = {}, ka[8] = {};
  for (int i = 0; i < 256; ++i) {
    float wq = Wq[i * 256 + j], wk = Wk[i * 256 + j];
    #pragma unroll
    for (int r = 0; r < 8; ++r) {
      qa[r] = __fmaf_rn(sx[r][i], wq, qa[r]);
      ka[r] = __fmaf_rn(sx[r][i], wk, ka[r]);
    }
  }
  #pragma unroll
  for (int r = 0; r < 8; ++r) { sq[r][j] = qa[r]; sk[r][j] = ka[r]; }
  __syncthreads();
  if (j < 64) {
    const int r = j >> 3, head = j & 7;
    const float* qq = &sq[r][head * 32];
    const float* kk = &sk[r][head * 32];
    float s0 = 0.0f, s1 = 0.0f, s2 = 0.0f, s3 = 0.0f;
    #pragma unroll 1
    for (int d = 0; d < 32; d += 4) {
      s0 = __fadd_rn(s0, __fmul_rn(qq[d + 0], kk[d + 0]));
      s1 = __fadd_rn(s1, __fmul_rn(qq[d + 1], kk[d + 1]));
      s2 = __fadd_rn(s2, __fmul_rn(qq[d + 2], kk[d + 2]));
      s3 = __fadd_rn(s3, __fmul_rn(qq[d + 3], kk[d + 3]));
    }
    float p = __fadd_rn(__fadd_rn(s0, s2), __fadd_rn(s1, s3));
    float hval = __fdiv_rn(p, sqrtf(32.0f));
    float inv = __fdiv_rn(1.0f, __fadd_rn(hval, 1e-6f));
    const int row = r0 + r;
    const int b = row / P, pos = row - b * P;
    hout[((size_t)b * 8 + head) * P + pos] = inv;
  }
}

// e_hval (cols 0/256) and einv_hval (cols 768/1024) from P1 [12288][1280].
__global__ __launch_bounds__(256) void dot2_hval(
    const float* __restrict__ P1, float* __restrict__ hE,
    float* __restrict__ hEi) {
  const int wv = threadIdx.x >> 6, lane = threadIdx.x & 63;
  const int row = blockIdx.x * 4 + wv;
  const float* base = P1 + (size_t)row * 1280 + lane * 4;
  f32x4 q = *(const f32x4*)(base);
  f32x4 k = *(const f32x4*)(base + 256);
  float p = q[0] * k[0] + q[1] * k[1] + q[2] * k[2] + q[3] * k[3];
  p += __shfl_xor(p, 1); p += __shfl_xor(p, 2); p += __shfl_xor(p, 4);
  f32x4 q2 = *(const f32x4*)(base + 768);
  f32x4 k2 = *(const f32x4*)(base + 1024);
  float p2 = q2[0] * k2[0] + q2[1] * k2[1] + q2[2] * k2[2] + q2[3] * k2[3];
  p2 += __shfl_xor(p2, 1); p2 += __shfl_xor(p2, 2); p2 += __shfl_xor(p2, 4);
  if ((lane & 7) == 0) {
    const int head = lane >> 3;
    const int b = row / 6144, pos = row % 6144;
    hE[((size_t)b * 8 + head) * 6144 + pos] = p * 0.17677669529663687f;
    hEi[((size_t)b * 8 + head) * 6144 + pos] = p2 * 0.17677669529663687f;
  }
}

// hval = rowwise per-head dot of fp32 Q,K (ld = row stride). One wave/row.
__global__ __launch_bounds__(256) void dot_hval(
    const float* __restrict__ Q, const float* __restrict__ K,
    float* __restrict__ hout, int P, int ld) {
  const int wv = threadIdx.x >> 6, lane = threadIdx.x & 63;
  const int row = blockIdx.x * 4 + wv;
  f32x4 q = *(const f32x4*)(Q + (size_t)row * ld + lane * 4);
  f32x4 k = *(const f32x4*)(K + (size_t)row * ld + lane * 4);
  float p = q[0] * k[0] + q[1] * k[1] + q[2] * k[2] + q[3] * k[3];
  p += __shfl_xor(p, 1); p += __shfl_xor(p, 2); p += __shfl_xor(p, 4);
  if ((lane & 7) == 0) {
    const int head = lane >> 3;
    const int b = row / P, pos = row % P;
    hout[((size_t)b * 8 + head) * P + pos] = p * 0.17677669529663687f;
  }
}

// ---------------------------------------------------------------------------
extern "C" void kernel_launch(void* const* d_in, const int* in_sizes, int n_in,
                              void* d_out, int out_size, void* d_ws, size_t ws_size,
                              hipStream_t stream) {
  const float* x_v = (const float*)d_in[0];
  const float* x_e = (const float*)d_in[1];
  const float* x_f = (const float*)d_in[2];
  const float* d0  = (const float*)d_in[3];   // (2, 6144, 2048)
  const float* d1  = (const float*)d_in[4];   // (2, 4096, 6144)
  const float* W_vq = (const float*)d_in[5];
  const float* W_vk = (const float*)d_in[6];
  float* out = (float*)d_out;

  const int NV = 2048, ME = 6144, KF = 4096;
  const float* NF = nullptr;
  const unsigned short* NUS = nullptr;

  char* ws = (char*)d_ws;
  size_t o = 0;
  auto alloc = [&](size_t bytes) { size_t r = o; o = (o + bytes + 255) & ~255ULL; return r; };

  unsigned short* Wcat5_hi = (unsigned short*)(ws + alloc(1280 * 256 * 2));
  unsigned short* Wcat5_lo = (unsigned short*)(ws + alloc(1280 * 256 * 2));
  unsigned short* W3_hi = (unsigned short*)(ws + alloc(512 * 256 * 2));
  unsigned short* Wo_hi = (unsigned short*)(ws + alloc(256 * 256 * 2));
  unsigned short* Wo_lo = (unsigned short*)(ws + alloc(256 * 256 * 2));
  float* pHvE  = (float*)(ws + alloc(2 * 8 * ME * 4));
  float* pHvEi = (float*)(ws + alloc(2 * 8 * ME * 4));
  float* pHvF  = (float*)(ws + alloc(2 * 8 * KF * 4));
  float* pHvV  = (float*)(ws + alloc(2 * 8 * NV * 4));
  unsigned short* d1T_hi = (unsigned short*)(ws + alloc((size_t)2 * ME * KF * 2));   // [2][6144][4096]
  unsigned short* d1N_hi = (unsigned short*)(ws + alloc((size_t)2 * KF * ME * 2));   // [2][4096][6144]
  unsigned short* d0T_hi = (unsigned short*)(ws + alloc((size_t)2 * NV * ME * 2));   // [2][2048][6144]
  unsigned short* d0T_lo = (unsigned short*)(ws + alloc((size_t)2 * NV * ME * 2));
  unsigned short* d0N_hi = (unsigned short*)(ws + alloc((size_t)2 * ME * NV * 2));   // [2][6144][2048]
  unsigned short* d0N_lo = (unsigned short*)(ws + alloc((size_t)2 * ME * NV * 2));
  unsigned short* eVT_hi = (unsigned short*)(ws + alloc((size_t)2 * 256 * ME * 2));  // [2][256][6144]
  unsigned short* Y0T_hi = (unsigned short*)(ws + alloc((size_t)2 * 256 * ME * 2));
  unsigned short* Y0T_lo = (unsigned short*)(ws + alloc((size_t)2 * 256 * ME * 2));
  unsigned short* T1sT_hi = (unsigned short*)(ws + alloc((size_t)2 * 256 * KF * 2)); // [2][256][4096]
  unsigned short* T3sT_hi = (unsigned short*)(ws + alloc((size_t)2 * 256 * NV * 2)); // [2][256][2048]
  unsigned short* T3sT_lo = (unsigned short*)(ws + alloc((size_t)2 * 256 * NV * 2));
  float* pP1 = (float*)(ws + alloc((size_t)12288 * 1280 * 4));   // e projections (N=1280)
  float* pP3 = (float*)(ws + alloc((size_t)8192 * 512 * 4));     // f projections
  float* pTp1 = (float*)(ws + alloc((size_t)2 * 6 * 256 * KF * 4));   // T1^T slabs
  float* pTp3 = (float*)(ws + alloc((size_t)2 * 12 * 256 * NV * 4));  // T3^T slabs
  float* pT2p = (float*)(ws + alloc((size_t)2 * 4 * ME * 256 * 4));
  float* pT4p = (float*)(ws + alloc((size_t)2 * 4 * ME * 256 * 4));

  dim3 blk(256);

  // --- batched weight transposes -> bf16 [n][k] ---
  WTab tab;
  tab.s[0] = (const float*)d_in[7];  tab.h[0] = Wcat5_hi;            tab.l[0] = Wcat5_lo;            // eq
  tab.s[1] = (const float*)d_in[8];  tab.h[1] = Wcat5_hi + 65536;    tab.l[1] = Wcat5_lo + 65536;    // ek
  tab.s[2] = (const float*)d_in[11]; tab.h[2] = Wcat5_hi + 131072;   tab.l[2] = Wcat5_lo + 131072;   // ev
  tab.s[3] = (const float*)d_in[9];  tab.h[3] = Wcat5_hi + 196608;   tab.l[3] = Wcat5_lo + 196608;   // einvq
  tab.s[4] = (const float*)d_in[10]; tab.h[4] = Wcat5_hi + 262144;   tab.l[4] = Wcat5_lo + 262144;   // einvk
  tab.s[5] = (const float*)d_in[12]; tab.h[5] = W3_hi;               tab.l[5] = nullptr;             // fq
  tab.s[6] = (const float*)d_in[13]; tab.h[6] = W3_hi + 65536;       tab.l[6] = nullptr;             // fk
  tab.s[7] = (const float*)d_in[14]; tab.h[7] = Wo_hi;               tab.l[7] = Wo_lo;               // o
  wxpose<<<dim3(4, 4, 8), blk, 0, stream>>>(tab);

  // --- d-matrix conversions (transposed + natural bf16, one read each) ---
  xpose_d1<<<dim3(64, 96, 2), blk, 0, stream>>>(d1, d1T_hi, d1N_hi);
  xpose_d0<<<dim3(96, 32, 2), blk, 0, stream>>>(d0, d0T_hi, d0T_lo, d0N_hi, d0N_lo);

  // --- v hval (np-fp32 exact) ---
  vproj_hval_np<<<512, blk, 0, stream>>>(x_v, W_vq, W_vk, pHvV, NV);

  // --- projections: P1 = x_e @ [eq|ek|ev|einvq|einvk] (split), P3 = x_f @ [fq|fk] ---
  gemm_ws<false, true, false><<<dim3(96, 10, 1), blk, 0, stream>>>(
      x_e, NUS, NUS, Wcat5_hi, Wcat5_lo, pP1, 256, 256, 256, 1, 0, 0, 0);
  dot2_hval<<<3072, blk, 0, stream>>>(pP1, pHvE, pHvEi);
  xpose_ev<<<dim3(96, 4, 2), blk, 0, stream>>>(pP1, eVT_hi, Y0T_hi, Y0T_lo, pHvE);
  gemm_ws<false, false, false><<<dim3(64, 4, 1), blk, 0, stream>>>(
      x_f, NUS, NUS, W3_hi, NUS, pP3, 256, 256, 256, 1, 0, 0, 0);
  dot_hval<<<2048, blk, 0, stream>>>(pP3, pP3 + 256, pHvF, KF, 512);

  // --- T1 || T3 (independent big GEMMs, tail overlap) ---
  // T1^T = eVT @ d1N (plain), S=6 -> [2][6][256][4096]
  gemm_ws<true, false, true><<<dim3(2, 32, 12), blk, 0, stream>>>(
      NF, eVT_hi, NUS, d1N_hi, NUS, pTp1, ME, ME, ME, 6,
      256LL * ME, (long long)KF * ME, 256LL * KF);
  // T3^T = Y0T @ d0T (split), S=12 -> [2][12][256][2048]
  gemm_ws<true, true, true><<<dim3(2, 16, 24), blk, 0, stream>>>(
      NF, Y0T_hi, Y0T_lo, d0T_hi, d0T_lo, pTp3, ME, ME, ME, 12,
      256LL * ME, (long long)NV * ME, 256LL * NV);

  // --- reductions + scale + cvt ---
  rsc_cvt<<<2048, blk, 0, stream>>>(pTp1, T1sT_hi, nullptr, pHvF, 6, 256, KF);
  rsc_cvt<<<1024, blk, 0, stream>>>(pTp3, T3sT_hi, T3sT_lo, pHvV, 12, 256, NV);

  // --- T2 || T4 ---
  // T2 = d1T @ T1s (plain), S=4 -> [2][4][6144][256]
  gemm_ws<true, false, false><<<dim3(48, 2, 8), blk, 0, stream>>>(
      NF, d1T_hi, NUS, T1sT_hi, NUS, pT2p, KF, KF, KF, 4,
      (long long)ME * KF, 256LL * KF, (long long)ME * 256);
  // T4 = d0N @ T3s (split), S=4 -> [2][4][6144][256]
  gemm_ws<true, true, false><<<dim3(48, 2, 8), blk, 0, stream>>>(
      NF, d0N_hi, d0N_lo, T3sT_hi, T3sT_lo, pT4p, NV, NV, NV, 4,
      (long long)ME * NV, 256LL * NV, (long long)ME * 256);

  // --- fused combine + output projection ---
  gemm_out<<<dim3(96, 2, 1), blk, 0, stream>>>(pT2p, pT4p, pHvEi, Wo_hi, Wo_lo, out);
}